// Round 10
// baseline (1641.982 us; speedup 1.0000x reference)
//
#include <hip/hip_runtime.h>
#include <math.h>

#define NN 50000
#define HH 256
#define RR 460
#define TT 3
#define EE 100000
#define PP 3
#define SLOPE 0.22916666666666666f
#define NBIN (RR + NN)           // per-t bins: 50460
#define NBIN3 (3*NBIN)           // batched bins

typedef __bf16 bf16_t;
typedef bf16_t bf16x8 __attribute__((ext_vector_type(8)));
typedef float f32x4 __attribute__((ext_vector_type(4)));

static const size_t NHf = (size_t)NN * HH;   // 12.8M elements

__device__ __forceinline__ float sigm(float x){ return 1.0f/(1.0f+__expf(-x)); }
__device__ __forceinline__ float leaky(float x){ return (x >= 0.f) ? x : SLOPE*x; }

__device__ __forceinline__ void gload_lds16(const void* g, void* l){
  __builtin_amdgcn_global_load_lds((const __attribute__((address_space(1))) void*)g,
                                   (__attribute__((address_space(3))) void*)l, 16, 0, 0);
}

// ---------------- merged weight transposes (sub fused for Wd): 8 jobs via blockIdx.z ----------------
// bstT0 [512][512]: rows 0-255 = [Wn0^T | Wl0^T]; rows 256-511 = [0 | timW^T] (zeros via memset)
// bstT1 [256][512]: [Wn1^T | Wl1^T]
__global__ __launch_bounds__(256) void tconv_all_k(
    const float* __restrict__ Wn, const float* __restrict__ Wl, const float* __restrict__ We,
    const float* __restrict__ timW, const float* __restrict__ globW,
    bf16_t* __restrict__ bstT0, bf16_t* __restrict__ bstT1,
    bf16_t* __restrict__ wdT, bf16_t* __restrict__ globT){
  int z = blockIdx.z;
  const float* in; const float* in2 = nullptr; bf16_t* outp; int ldout;
  switch(z){
    case 0: in = Wn;           outp = bstT0;                         ldout = 512; break;
    case 1: in = Wl;           outp = bstT0 + 256;                   ldout = 512; break;
    case 2: in = Wn + 65536;   outp = bstT1;                         ldout = 512; break;
    case 3: in = Wl + 65536;   outp = bstT1 + 256;                   ldout = 512; break;
    case 4: in = We;          in2 = Wl;         outp = wdT;          ldout = 256; break;
    case 5: in = We + 65536;  in2 = Wl + 65536; outp = wdT + 65536;  ldout = 256; break;
    case 6: in = timW;  outp = bstT0 + (size_t)256*512 + 256;        ldout = 512; break;
    default:in = globW; outp = globT;                                ldout = 256; break;
  }
  __shared__ float tile[32][33];
  int n0 = blockIdx.x*32, k0 = blockIdx.y*32;
  int tx = threadIdx.x & 31, ty = threadIdx.x >> 5;
  #pragma unroll
  for (int j=0;j<4;j++){
    size_t idx = (size_t)(k0+ty+j*8)*256 + n0+tx;
    float v = in[idx];
    if (in2) v -= in2[idx];
    tile[ty+j*8][tx] = v;
  }
  __syncthreads();
  #pragma unroll
  for (int j=0;j<4;j++)
    outp[(size_t)(n0+ty+j*8)*ldout + k0+tx] = (bf16_t)tile[tx][ty+j*8];
}

// ---------------- merged row copy+convert jobs via blockIdx.y ----------------
__global__ __launch_bounds__(256) void copyall_k(const float* __restrict__ gW_ih,
    const float* __restrict__ gW_hh, const float* __restrict__ W_hp, const float* __restrict__ emb_rel,
    bf16_t* __restrict__ wihAT, bf16_t* __restrict__ wihBT, bf16_t* __restrict__ whhT,
    bf16_t* __restrict__ whpT, bf16_t* __restrict__ h0b){
  int r = blockIdx.x, c = threadIdx.x, y = blockIdx.y;
  if (y == 0)      wihAT[(size_t)r*256+c] = (bf16_t)gW_ih[(size_t)r*512 + c];
  else if (y == 1) wihBT[(size_t)r*256+c] = (bf16_t)gW_ih[(size_t)r*512 + 256 + c];
  else if (y == 2) whhT[(size_t)r*256+c]  = (bf16_t)gW_hh[(size_t)r*256 + c];
  else if (y == 3){ if (r < 256) whpT[(size_t)r*256+c] = (bf16_t)W_hp[(size_t)r*259 + c]; }
  else            { if (r < RR)  h0b[(size_t)r*256+c]  = (bf16_t)emb_rel[(size_t)r*256 + c]; }
}

// ---------------- misc small setup: WP extract + b_ov ----------------
__global__ __launch_bounds__(256) void misc_k(const float* __restrict__ W_hp, float* __restrict__ WP,
    const float* __restrict__ W_o, const float* __restrict__ b_v, const float* __restrict__ b_o,
    float* __restrict__ b_ov){
  if (blockIdx.x == 0){
    int j = threadIdx.x;
    #pragma unroll
    for (int p=0;p<PP;p++) WP[p*HH + j] = W_hp[(size_t)j*259 + HH + p];
  } else {
    int n = threadIdx.x;
    float s = b_o[n];
    for (int j=0;j<256;j++) s += W_o[(size_t)n*256+j]*b_v[j];
    b_ov[n] = s;
  }
}

// ---------------- row copy+convert (wovT after sgemm) ----------------
__global__ __launch_bounds__(256) void copy_bfw_k(const float* __restrict__ in, bf16_t* __restrict__ outp){
  int r = blockIdx.x, c = threadIdx.x;
  outp[(size_t)r*HH + c] = (bf16_t)in[(size_t)r*HH + c];
}

// ---------------- f32 SGEMM (setup: WovF only) ----------------
__global__ __launch_bounds__(256) void sgemm_k(const float* __restrict__ A, const float* __restrict__ B,
                                               float* __restrict__ C, int M, int N, int K){
  __shared__ float As[16][128];
  __shared__ float Bs[16][64];
  int tid = threadIdx.x;
  int tx = tid & 15, ty = tid >> 4;
  int rowBase = blockIdx.x * 128;
  int colBase = blockIdx.y * 64;
  float acc[8][4];
  #pragma unroll
  for (int i=0;i<8;i++)
    #pragma unroll
    for (int j=0;j<4;j++) acc[i][j]=0.f;
  for (int k0=0;k0<K;k0+=16){
    #pragma unroll
    for (int ss=0; ss<2; ss++){
      int s = tid + ss*256;
      int r = s >> 2;
      int kk = (s & 3)*4;
      float4 v = make_float4(0.f,0.f,0.f,0.f);
      int grow = rowBase + r;
      if (grow < M) v = *(const float4*)(A + (size_t)grow*K + k0 + kk);
      As[kk+0][r]=v.x; As[kk+1][r]=v.y; As[kk+2][r]=v.z; As[kk+3][r]=v.w;
    }
    {
      int r = tid >> 4, cc = (tid & 15)*4;
      float4 v = *(const float4*)(B + (size_t)(k0+r)*N + colBase + cc);
      *(float4*)&Bs[r][cc] = v;
    }
    __syncthreads();
    #pragma unroll
    for (int kk=0;kk<16;kk++){
      float a[8], b[4];
      *(float4*)&a[0] = *(const float4*)&As[kk][ty*8];
      *(float4*)&a[4] = *(const float4*)&As[kk][ty*8+4];
      *(float4*)&b[0] = *(const float4*)&Bs[kk][tx*4];
      #pragma unroll
      for (int i=0;i<8;i++)
        #pragma unroll
        for (int j=0;j<4;j++)
          acc[i][j] = fmaf(a[i], b[j], acc[i][j]);
    }
    __syncthreads();
  }
  #pragma unroll
  for (int i=0;i<8;i++){
    int gr = rowBase + ty*8 + i;
    if (gr >= M) continue;
    float4 v = make_float4(acc[i][0], acc[i][1], acc[i][2], acc[i][3]);
    *(float4*)(C + (size_t)gr*N + colBase + tx*4) = v;
  }
}

// ---------------- bf16 MFMA GEMM (BM=BN=128, BK=64, 4 waves 2x2), fused epilogues ----------------
// C[M][N] = A[M][K] @ Bt[N][K]^T.
// SPLITA: K=512, k<256 from A0, k>=256 from A1 (both stride 256).
// EPI: 0 plain(+bias); 2 tanh(v+pos+bias) [e1=pos, e2=WP]; 3 gate-blend: g=sigm(v+bias),
//      C=g*eb+(1-g)*e1; 4 deg-aware leaky; 5 deg0 fix (rows via z, v=leaky(Cb_raw+v));
//      7 sigm(v+bias)->bf16; 8 v += e1-matrix;
//      9 dual: cols<256 deg-leaky->Cb (no bias), cols>=256 sigm(v+bias[col-256])->eb.
template<int EPI, int WF32, int WBF, int HASB, int SPLITA>
__global__ __launch_bounds__(256) void mgemm_k(
    const bf16_t* __restrict__ A0, const bf16_t* __restrict__ A1,
    const bf16_t* __restrict__ Bt,
    float* __restrict__ C, bf16_t* __restrict__ Cb, const float* __restrict__ bias,
    int M, int N, int K,
    const float* __restrict__ e1, const float* __restrict__ e2, bf16_t* __restrict__ eb,
    const int* __restrict__ degp, const int* __restrict__ z, const int* __restrict__ nzp){
  int rowBase = blockIdx.x * 128;
  int nzv = 0;
  if (EPI == 5){
    nzv = nzp[0];
    if (rowBase >= nzv) return;
  }
  __shared__ bf16_t As[128*64];
  __shared__ bf16_t Bs[128*64];
  int tid = threadIdx.x;
  int lane = tid & 63, w = tid >> 6;
  int wm = w >> 1, wn = w & 1;
  int colBase = blockIdx.y * 128;
  f32x4 acc[4][4] = {};

  int lrow = lane >> 3;          // 0..7 within the wave's 8-row group
  int p    = lane & 7;           // phys 16B seg
  int arow[4];
  #pragma unroll
  for (int c = 0; c < 4; c++){
    int gr = rowBase + c*32 + w*8 + lrow;
    if (EPI == 5) arow[c] = z[min(gr, nzv-1)];
    else          arow[c] = min(gr, M-1);
  }
  for (int k0 = 0; k0 < K; k0 += 64){
    const bf16_t* Ap; int koff; size_t lda;
    if (SPLITA){ Ap = (k0 < 256) ? A0 : A1; koff = k0 & 255; lda = 256; }
    else       { Ap = A0; koff = k0; lda = (size_t)K; }
    #pragma unroll
    for (int c = 0; c < 4; c++){
      int r = c*32 + w*8 + lrow;
      int s = p ^ (r & 7);                     // both-sides swizzle
      gload_lds16(Ap + (size_t)arow[c]*lda + koff + s*8, As + (size_t)(c*32 + w*8)*64);
      int gb = colBase + r;                    // Bt has >= gridDim.y*128 rows always
      gload_lds16(Bt + (size_t)gb*K + k0 + s*8, Bs + (size_t)(c*32 + w*8)*64);
    }
    asm volatile("s_waitcnt vmcnt(0)" ::: "memory");
    __syncthreads();
    #pragma unroll
    for (int kk = 0; kk < 2; kk++){
      bf16x8 af[4], bfr[4];
      int sg = kk*4 + (lane >> 4);             // logical seg 0..7
      #pragma unroll
      for (int i = 0; i < 4; i++){
        int r = wm*64 + i*16 + (lane & 15);
        af[i] = *(const bf16x8*)(As + r*64 + (sg ^ (r & 7))*8);
      }
      #pragma unroll
      for (int j = 0; j < 4; j++){
        int rn = wn*64 + j*16 + (lane & 15);
        bfr[j] = *(const bf16x8*)(Bs + rn*64 + (sg ^ (rn & 7))*8);
      }
      #pragma unroll
      for (int i = 0; i < 4; i++)
        #pragma unroll
        for (int j = 0; j < 4; j++)
          acc[i][j] = __builtin_amdgcn_mfma_f32_16x16x32_bf16(af[i], bfr[j], acc[i][j], 0, 0, 0);
    }
    __syncthreads();
  }
  // ---- epilogue ----
  int colv[4]; float bb[4], wp0[4], wp1[4], wp2[4];
  #pragma unroll
  for (int j = 0; j < 4; j++){
    colv[j] = colBase + wn*64 + j*16 + (lane & 15);
    if (EPI == 9) bb[j] = (HASB && colv[j] >= 256) ? bias[colv[j]-256] : 0.f;
    else          bb[j] = HASB ? bias[colv[j]] : 0.f;
    if (EPI == 2){ wp0[j] = e2[colv[j]]; wp1[j] = e2[256+colv[j]]; wp2[j] = e2[512+colv[j]]; }
  }
  #pragma unroll
  for (int i = 0; i < 4; i++){
    #pragma unroll
    for (int q = 0; q < 4; q++){
      int grt = rowBase + wm*64 + i*16 + ((lane >> 4) << 2) + q;
      if (EPI == 5){ if (grt >= nzv) continue; }
      else         { if (grt >= M) continue; }
      int orow = (EPI == 5) ? z[grt] : grt;
      int dflag = 0;
      if (EPI == 4 || EPI == 9) dflag = degp[orow];
      float p0=0.f, p1=0.f, p2=0.f;
      if (EPI == 2){ p0 = e1[(size_t)grt*3]; p1 = e1[(size_t)grt*3+1]; p2 = e1[(size_t)grt*3+2]; }
      #pragma unroll
      for (int j = 0; j < 4; j++){
        float v = acc[i][j][q] + bb[j];
        if (EPI == 9){
          if (colv[j] < 256){
            float vv = (dflag > 0) ? leaky(v) : v;
            Cb[(size_t)orow*256 + colv[j]] = (bf16_t)vv;
          } else {
            eb[(size_t)orow*256 + (colv[j]-256)] = (bf16_t)sigm(v);
          }
          continue;
        }
        size_t idx = (size_t)orow*N + colv[j];
        if (EPI == 2) v = tanhf(v + p0*wp0[j] + p1*wp1[j] + p2*wp2[j]);
        if (EPI == 3){
          float g = sigm(v);
          v = g*(float)eb[idx] + (1.f-g)*e1[idx];
        }
        if (EPI == 4) v = (dflag > 0) ? leaky(v) : v;
        if (EPI == 5){
          float praw = (float)Cb[idx];
          v = leaky(praw + v);
        }
        if (EPI == 7) v = sigm(v);
        if (EPI == 8) v += e1[idx];
        if (WF32) C[idx] = v;
        if (WBF)  Cb[idx] = (bf16_t)v;
      }
    }
  }
}

// ---------------- row-wise L2 normalize -> f32 + bf16 (setup) ----------------
__global__ __launch_bounds__(256) void l2norm_k(const float* __restrict__ in, float* __restrict__ outf,
                                                bf16_t* __restrict__ outb){
  int i = blockIdx.x, c = threadIdx.x;
  size_t idx = (size_t)i*HH + c;
  float v = in[idx];
  float ss = v*v;
  #pragma unroll
  for (int o=32;o;o>>=1) ss += __shfl_down(ss, o);
  __shared__ float red[4];
  if ((threadIdx.x & 63)==0) red[threadIdx.x>>6] = ss;
  __syncthreads();
  float tot = red[0]+red[1]+red[2]+red[3];
  float nv = v / fmaxf(sqrtf(tot), 1e-12f);
  outf[idx] = nv;
  outb[idx] = (bf16_t)nv;
}

// ---------------- batched combined histogram over all 3 t's ----------------
__global__ __launch_bounds__(256) void hist3_k(const int* __restrict__ r_seg, const int* __restrict__ dst,
                                               int* __restrict__ cnt){
  int q = blockIdx.x*256 + threadIdx.x;
  if (q >= 3*2*EE) return;
  int t = q / (2*EE);
  int e = q - t*2*EE;
  if (e < EE) atomicAdd(cnt + t*NBIN + r_seg[(size_t)t*EE + e], 1);
  else        atomicAdd(cnt + t*NBIN + RR + dst[(size_t)t*EE + (e-EE)], 1);
}

// ---------------- hierarchical exclusive scan ----------------
__global__ __launch_bounds__(1024) void scan1_k(const int* __restrict__ cnt, int* __restrict__ start,
                                                int* __restrict__ bsum, int n){
  __shared__ int s[1024];
  int t = blockIdx.x*1024 + threadIdx.x;
  int v = (t < n) ? cnt[t] : 0;
  s[threadIdx.x] = v;
  __syncthreads();
  for (int off = 1; off < 1024; off <<= 1){
    int x = (threadIdx.x >= off) ? s[threadIdx.x - off] : 0;
    __syncthreads();
    s[threadIdx.x] += x;
    __syncthreads();
  }
  if (t < n) start[t] = s[threadIdx.x] - v;
  if (threadIdx.x == 1023) bsum[blockIdx.x] = s[1023];
}
__global__ __launch_bounds__(256) void scan2_k(const int* __restrict__ bsum, int* __restrict__ boff,
                                               int* __restrict__ start, int nb, int n){
  __shared__ int s[256];
  int t = threadIdx.x;
  int v = (t < nb) ? bsum[t] : 0;
  s[t] = v;
  __syncthreads();
  for (int off = 1; off < 256; off <<= 1){
    int x = (t >= off) ? s[t-off] : 0;
    __syncthreads();
    s[t] += x;
    __syncthreads();
  }
  if (t < nb) boff[t] = s[t] - v;
  if (t == 255) start[n] = s[255];
}
__global__ __launch_bounds__(1024) void scan3_k(int* __restrict__ start, int* __restrict__ cur,
                                                const int* __restrict__ boff, int n){
  int t = blockIdx.x*1024 + threadIdx.x;
  if (t < n){
    int v = start[t] + boff[blockIdx.x];
    start[t] = v;
    cur[t] = v;
  }
}

// ---------------- batched CSR fill (dst side packs src|ety<<16 into u32) ----------------
__global__ __launch_bounds__(256) void fill3_k(const int* __restrict__ r_seg, const int* __restrict__ r_to_e,
    const int* __restrict__ dst, const int* __restrict__ src, const int* __restrict__ ety,
    int* __restrict__ cur, int* __restrict__ rnode, unsigned* __restrict__ dpack){
  int q = blockIdx.x*256 + threadIdx.x;
  if (q >= 3*2*EE) return;
  int t = q / (2*EE);
  int e = q - t*2*EE;
  if (e < EE){
    size_t ge = (size_t)t*EE + e;
    int pp = atomicAdd(cur + t*NBIN + r_seg[ge], 1);
    rnode[pp - EE*t] = r_to_e[ge];
  } else {
    size_t ge = (size_t)t*EE + (e - EE);
    int pp = atomicAdd(cur + t*NBIN + RR + dst[ge], 1);
    dpack[pp - EE*(t+1)] = (unsigned)src[ge] | ((unsigned)ety[ge] << 16);
  }
}

// ---------------- batched compact deg-0 node lists (wave-aggregated atomics) ----------------
__global__ __launch_bounds__(256) void compact3_k(const int* __restrict__ cnt, int* __restrict__ zAll,
                                                  int* __restrict__ nz){
  int q = blockIdx.x*256 + threadIdx.x;
  int lane = threadIdx.x & 63;
  bool valid = q < 3*NN;
  int qc = valid ? q : 3*NN - 1;
  int t = qc / NN, d = qc - t*NN;
  bool pred = valid && (cnt[t*NBIN + RR + d] == 0);
  int tA = __shfl(t, 0), tB = __shfl(t, 63);
  if (tA == tB){
    unsigned long long m = __ballot(pred);
    int total = __popcll(m);
    int base = 0;
    if (lane == 0 && total > 0) base = atomicAdd(nz + tA, total);
    base = __shfl(base, 0);
    if (pred){
      int myoff = __popcll(m & ((1ULL << lane) - 1ULL));
      zAll[(size_t)tA*NN + base + myoff] = d;
    }
  } else {
    if (pred){
      int pp = atomicAdd(nz + t, 1);
      zAll[(size_t)t*NN + pp] = d;
    }
  }
}

// per-relation mean of h rows (bf16 out)
__global__ __launch_bounds__(256) void rmean_k(const int* __restrict__ startT, const int* __restrict__ rnode,
    const bf16_t* __restrict__ hb, bf16_t* __restrict__ meanb, int rbase){
  int r = blockIdx.x, c = threadIdx.x;
  int s0 = startT[r] - rbase, s1 = startT[r+1] - rbase;
  float acc = 0.f, acc2 = 0.f;
  int i = s0;
  for (; i + 1 < s1; i += 2){
    acc  += (float)hb[(size_t)rnode[i]*HH + c];
    acc2 += (float)hb[(size_t)rnode[i+1]*HH + c];
  }
  if (i < s1) acc += (float)hb[(size_t)rnode[i]*HH + c];
  acc += acc2;
  int cnt = s1 - s0;
  meanb[(size_t)r*HH + c] = (bf16_t)((cnt > 0) ? acc/(float)cnt : 0.f);
}

// ---------------- GRU gates + row l2norm, in-place h0 (f32) + bf16 shadow ----------------
__global__ __launch_bounds__(256) void gru_gate_k(const float* __restrict__ gi,
    const float* __restrict__ ghb, float* __restrict__ h0, bf16_t* __restrict__ h0b){
  int r = blockIdx.x, c = threadIdx.x;
  float ir = gi[(size_t)r*768 + c],       hr = ghb[(size_t)r*768 + c];
  float iz = gi[(size_t)r*768 + 256 + c], hz = ghb[(size_t)r*768 + 256 + c];
  float in_ = gi[(size_t)r*768 + 512 + c], hn = ghb[(size_t)r*768 + 512 + c];
  float rg = sigm(ir + hr);
  float z  = sigm(iz + hz);
  float n  = tanhf(in_ + rg*hn);
  float hp = h0[(size_t)r*HH + c];
  float v = (1.f - z)*n + z*hp;
  float ss = v*v;
  #pragma unroll
  for (int o=32;o;o>>=1) ss += __shfl_down(ss, o);
  __shared__ float red[4];
  if ((threadIdx.x & 63)==0) red[threadIdx.x>>6] = ss;
  __syncthreads();
  float tot = red[0]+red[1]+red[2]+red[3];
  float nv = v / fmaxf(sqrtf(tot), 1e-12f);
  h0[(size_t)r*HH + c] = nv;
  h0b[(size_t)r*HH + c] = (bf16_t)nv;
}

// ---------------- gather mean messages (packed u32 edge payload) ----------------
__global__ __launch_bounds__(256) void gatherM_k(const bf16_t* __restrict__ nin,
    const bf16_t* __restrict__ h0b, const int* __restrict__ startT,
    const unsigned* __restrict__ dpack, bf16_t* __restrict__ Amean, int ebase){
  int w = threadIdx.x >> 6, ln = threadIdx.x & 63;
  int d = blockIdx.x*4 + w;
  if (d >= NN) return;
  int s0 = startT[RR + d] - ebase, s1 = startT[RR + d + 1] - ebase;
  int deg = s1 - s0;
  float a0=0.f, a1=0.f, a2=0.f, a3=0.f;
  for (int i = s0; i < s1; i++){
    unsigned se = dpack[i];
    int s = (int)(se & 0xffffu);
    int r = (int)(se >> 16);
    uint2 ra = *(const uint2*)(nin + (size_t)s*HH + ln*4);
    uint2 rb = *(const uint2*)(h0b + (size_t)r*HH + ln*4);
    a0 += __uint_as_float((ra.x & 0xffffu) << 16) + __uint_as_float((rb.x & 0xffffu) << 16);
    a1 += __uint_as_float(ra.x & 0xffff0000u)     + __uint_as_float(rb.x & 0xffff0000u);
    a2 += __uint_as_float((ra.y & 0xffffu) << 16) + __uint_as_float((rb.y & 0xffffu) << 16);
    a3 += __uint_as_float(ra.y & 0xffff0000u)     + __uint_as_float(rb.y & 0xffff0000u);
  }
  float inv = (deg > 0) ? 1.f/(float)deg : 0.f;
  bf16_t m[4] = { (bf16_t)(a0*inv), (bf16_t)(a1*inv), (bf16_t)(a2*inv), (bf16_t)(a3*inv) };
  *(uint2*)(Amean + (size_t)d*HH + ln*4) = *(const uint2*)m;
}

// ---------------- fused l2norm(nh2_bf) + time-gate h update (gate pre-sigmoided, bf16) ----------------
__global__ __launch_bounds__(256) void l2up_k(const bf16_t* __restrict__ nh2b, const bf16_t* __restrict__ sg,
    float* __restrict__ h, bf16_t* __restrict__ hb){
  int i = blockIdx.x, c = threadIdx.x;
  size_t idx = (size_t)i*HH + c;
  float v = (float)nh2b[idx];
  float ss = v*v;
  #pragma unroll
  for (int o=32;o;o>>=1) ss += __shfl_down(ss, o);
  __shared__ float red[4];
  if ((threadIdx.x & 63)==0) red[threadIdx.x>>6] = ss;
  __syncthreads();
  float tot = red[0]+red[1]+red[2]+red[3];
  float curn = v / fmaxf(sqrtf(tot), 1e-12f);
  float s = (float)sg[idx];
  float hn = s*curn + (1.f-s)*h[idx];
  h[idx] = hn;
  hb[idx] = (bf16_t)hn;
}

extern "C" void kernel_launch(void* const* d_in, const int* in_sizes, int n_in,
                              void* d_out, int out_size, void* d_ws, size_t ws_size,
                              hipStream_t stream) {
  const int*   src     = (const int*)  d_in[0];
  const int*   dst     = (const int*)  d_in[1];
  const int*   etype   = (const int*)  d_in[2];
  const int*   r_to_e  = (const int*)  d_in[3];
  const int*   r_seg   = (const int*)  d_in[4];
  const float* pos_enc = (const float*)d_in[5];
  const float* dyn_emb = (const float*)d_in[6];
  const float* emb_rel = (const float*)d_in[7];
  const float* gW_ih   = (const float*)d_in[8];
  const float* gW_hh   = (const float*)d_in[9];
  const float* gb_ih   = (const float*)d_in[10];
  const float* gb_hh   = (const float*)d_in[11];
  const float* W_neigh = (const float*)d_in[12];
  const float* W_loop  = (const float*)d_in[13];
  const float* W_evolve= (const float*)d_in[14];
  const float* W_hp    = (const float*)d_in[15];
  const float* b_hp    = (const float*)d_in[16];
  const float* W_v     = (const float*)d_in[17];
  const float* b_v     = (const float*)d_in[18];
  const float* W_o     = (const float*)d_in[19];
  const float* b_o     = (const float*)d_in[20];
  const float* time_W  = (const float*)d_in[21];
  const float* time_b  = (const float*)d_in[22];
  const float* glob_W  = (const float*)d_in[23];
  const float* glob_b  = (const float*)d_in[24];
  float* out = (float*)d_out;
  (void)in_sizes; (void)n_in; (void)out_size; (void)ws_size;

  char* ws = (char*)d_ws;
  size_t off = 0;
  auto allocB = [&](size_t bytes)->char*{
    char* pp = ws + off; off += (bytes + 255) & ~(size_t)255;
    return pp;
  };
  float*  h      = (float*) allocB(NHf*4);          // recurrent state f32
  float*  tmp    = (float*) allocB(NHf*4);          // Amean (bf16, 1st half) + sgate (bf16, 2nd half)
  bf16_t* h_bf   = (bf16_t*)allocB(NHf*2);
  bf16_t* nh_bf  = (bf16_t*)allocB(NHf*2);          // layer-0 out; aliased: attn_bf
  bf16_t* nh2_bf = (bf16_t*)allocB(NHf*2);
  bf16_t* gh_bf  = (bf16_t*)allocB(NHf*2);
  bf16_t* Amean  = (bf16_t*)tmp;
  bf16_t* sgate  = (bf16_t*)(tmp + NHf/2);
  bf16_t* attn_bf= nh_bf;

  float*  h0    = (float*) allocB((size_t)RR*HH*4);
  bf16_t* h0b   = (bf16_t*)allocB((size_t)RR*HH*2);
  bf16_t* meanb = (bf16_t*)allocB((size_t)RR*HH*2);
  float*  gi0   = (float*) allocB((size_t)RR*768*4);
  float*  gi    = (float*) allocB((size_t)RR*768*4);
  float*  ghb   = (float*) allocB((size_t)RR*768*4);
  bf16_t* wihAT = (bf16_t*)allocB((size_t)768*256*2);
  bf16_t* wihBT = (bf16_t*)allocB((size_t)768*256*2);
  bf16_t* whhT  = (bf16_t*)allocB((size_t)768*256*2);
  float*  WP    = (float*) allocB((size_t)PP*HH*4);
  float*  WovF  = (float*) allocB((size_t)HH*HH*4);
  float*  b_ov  = (float*) allocB((size_t)HH*4);
  bf16_t* bstT0 = (bf16_t*)allocB((size_t)512*512*2);    // L0 stack [Wn|Wl ; 0|tim]
  bf16_t* bstT1 = (bf16_t*)allocB((size_t)256*512*2);    // L1 stack [Wn|Wl]
  bf16_t* wdT   = (bf16_t*)allocB((size_t)2*HH*HH*2);    // per-layer (We-Wl)^T
  bf16_t* whpT  = (bf16_t*)allocB((size_t)HH*HH*2);
  bf16_t* wovT  = (bf16_t*)allocB((size_t)HH*HH*2);
  bf16_t* globT = (bf16_t*)allocB((size_t)HH*HH*2);
  int* cnt    = (int*)allocB((size_t)(NBIN3+4)*4);       // + nz[3] at tail
  int* start  = (int*)allocB((size_t)(NBIN3+1)*4);
  int* cur    = (int*)allocB((size_t)NBIN3*4);
  int* rnode  = (int*)allocB((size_t)3*EE*4);
  unsigned* dpack = (unsigned*)allocB((size_t)3*EE*4);
  int* zAll   = (int*)allocB((size_t)3*NN*4);
  int* bsum   = (int*)allocB(256*4);
  int* boff   = (int*)allocB(256*4);
  int* nz     = cnt + NBIN3;

  const int MT  = (NN + 127)/128;            // 391 row tiles
  const int NB3 = (NBIN3 + 1023)/1024;       // 148 scan blocks

  // ---- setup: weight prep + initial h/h0 + gi0 ----
  hipMemsetAsync(bstT0, 0, (size_t)512*512*2, stream);   // zero the [0|tim] padding
  copyall_k<<<dim3(768,5), 256, 0, stream>>>(gW_ih, gW_hh, W_hp, emb_rel,
                                             wihAT, wihBT, whhT, whpT, h0b);
  tconv_all_k<<<dim3(8,8,8), 256, 0, stream>>>(W_neigh, W_loop, W_evolve, time_W, glob_W,
                                               bstT0, bstT1, wdT, globT);
  misc_k<<<2, 256, 0, stream>>>(W_hp, WP, W_o, b_v, b_o, b_ov);
  sgemm_k<<<dim3(2,4), 256, 0, stream>>>(W_o, W_v, WovF, 256, 256, 256);
  copy_bfw_k<<<HH, 256, 0, stream>>>(WovF, wovT);
  l2norm_k<<<NN, 256, 0, stream>>>(dyn_emb, h, h_bf);
  hipMemcpyAsync(h0, emb_rel, (size_t)RR*HH*4, hipMemcpyDeviceToDevice, stream);
  // gi0 = emb_rel @ W_ih[:, :256]^T + b_ih   (h0b == emb_rel bf16 at this point)
  mgemm_k<0,1,0,1,0><<<dim3(4,6), 256, 0, stream>>>(h0b, nullptr, wihAT, gi0, nullptr, gb_ih,
      RR, 768, 256, nullptr, nullptr, nullptr, nullptr, nullptr, nullptr);

  // ---- batched CSR build for all 3 snapshots ----
  hipMemsetAsync(cnt, 0, (size_t)(NBIN3+4)*4, stream);
  hist3_k<<<(6*EE+255)/256, 256, 0, stream>>>(r_seg, dst, cnt);
  scan1_k<<<NB3, 1024, 0, stream>>>(cnt, start, bsum, NBIN3);
  scan2_k<<<1, 256, 0, stream>>>(bsum, boff, start, NB3, NBIN3);
  scan3_k<<<NB3, 1024, 0, stream>>>(start, cur, boff, NBIN3);
  fill3_k<<<(6*EE+255)/256, 256, 0, stream>>>(r_seg, r_to_e, dst, src, etype, cur, rnode, dpack);
  compact3_k<<<(3*NN+255)/256, 256, 0, stream>>>(cnt, zAll, nz);

  for (int t=0; t<TT; t++){
    const float* posT = pos_enc + (size_t)t*NN*PP;
    const int* startT = start + (size_t)t*NBIN;
    const int* degT   = cnt + (size_t)t*NBIN + RR;
    const int* zT     = zAll + (size_t)t*NN;
    const int* nzT    = nz + t;

    // ---- relation mean + GRU ----
    rmean_k<<<RR, 256, 0, stream>>>(startT, rnode, h_bf, meanb, EE*t);
    mgemm_k<8,1,0,0,0><<<dim3(4,6), 256, 0, stream>>>(meanb, nullptr, wihBT, gi, nullptr, nullptr,
        RR, 768, 256, gi0, nullptr, nullptr, nullptr, nullptr, nullptr);
    mgemm_k<0,1,0,1,0><<<dim3(4,6), 256, 0, stream>>>(h0b, nullptr, whhT, ghb, nullptr, gb_hh,
        RR, 768, 256, nullptr, nullptr, nullptr, nullptr, nullptr, nullptr);
    gru_gate_k<<<RR, 256, 0, stream>>>(gi, ghb, h0, h0b);

    // ---- RGCN layer 0 + fused time-gate (dual-output GEMM, N=512 via zero-padded B-stack) ----
    gatherM_k<<<(NN+3)/4, 256, 0, stream>>>(h_bf, h0b, startT, dpack, Amean, EE*(t+1));
    mgemm_k<9,0,0,1,1><<<dim3(MT,4), 256, 0, stream>>>(Amean, h_bf, bstT0, nullptr, nh_bf, time_b,
        NN, 256, 512, nullptr, nullptr, sgate, degT, nullptr, nullptr);
    mgemm_k<5,0,1,0,0><<<dim3(MT,2), 256, 0, stream>>>(h_bf, nullptr, wdT, nullptr, nh_bf, nullptr,
        NN, 256, 256, nullptr, nullptr, nullptr, nullptr, zT, nzT);

    // ---- RGCN layer 1 ----
    gatherM_k<<<(NN+3)/4, 256, 0, stream>>>(nh_bf, h0b, startT, dpack, Amean, EE*(t+1));
    mgemm_k<4,0,1,0,1><<<dim3(MT,2), 256, 0, stream>>>(Amean, nh_bf, bstT1, nullptr, nh2_bf, nullptr,
        NN, 256, 512, nullptr, nullptr, nullptr, degT, nullptr, nullptr);
    mgemm_k<5,0,1,0,0><<<dim3(MT,2), 256, 0, stream>>>(nh_bf, nullptr, wdT + (size_t)HH*HH, nullptr, nh2_bf, nullptr,
        NN, 256, 256, nullptr, nullptr, nullptr, nullptr, zT, nzT);

    // ---- attention chain ----
    mgemm_k<2,0,1,1,0><<<dim3(MT,2), 256, 0, stream>>>(nh2_bf, nullptr, whpT, nullptr, attn_bf, b_hp,
        NN, 256, 256, posT, WP, nullptr, nullptr, nullptr, nullptr);
    mgemm_k<0,0,1,1,0><<<dim3(MT,2), 256, 0, stream>>>(attn_bf, nullptr, wovT, nullptr, gh_bf, b_ov,
        NN, 256, 256, nullptr, nullptr, nullptr, nullptr, nullptr, nullptr);

    // ---- fused norm + time-gate h update (sgate from layer-0), glob gate + out blend ----
    l2up_k<<<NN, 256, 0, stream>>>(nh2_bf, sgate, h, h_bf);
    mgemm_k<3,1,0,1,0><<<dim3(MT,2), 256, 0, stream>>>(h_bf, nullptr, globT, out + (size_t)t*NHf, nullptr, glob_b,
        NN, 256, 256, h, nullptr, gh_bf, nullptr, nullptr, nullptr);
  }
}

// Round 11
// 1563.272 us; speedup vs baseline: 1.0503x; 1.0503x over previous
//
#include <hip/hip_runtime.h>
#include <math.h>

#define NN 50000
#define HH 256
#define RR 460
#define TT 3
#define EE 100000
#define PP 3
#define SLOPE 0.22916666666666666f
#define NBIN (RR + NN)           // per-t bins: 50460
#define NBIN3 (3*NBIN)           // batched bins

typedef __bf16 bf16_t;
typedef bf16_t bf16x8 __attribute__((ext_vector_type(8)));
typedef float f32x4 __attribute__((ext_vector_type(4)));

static const size_t NHf = (size_t)NN * HH;   // 12.8M elements

__device__ __forceinline__ float sigm(float x){ return 1.0f/(1.0f+__expf(-x)); }
__device__ __forceinline__ float leaky(float x){ return (x >= 0.f) ? x : SLOPE*x; }

__device__ __forceinline__ void gload_lds16(const void* g, void* l){
  __builtin_amdgcn_global_load_lds((const __attribute__((address_space(1))) void*)g,
                                   (__attribute__((address_space(3))) void*)l, 16, 0, 0);
}

// ---------------- merged weight transposes (sub fused for Wd): 8 jobs via blockIdx.z ----------------
__global__ __launch_bounds__(256) void tconv_all_k(
    const float* __restrict__ Wn, const float* __restrict__ Wl, const float* __restrict__ We,
    const float* __restrict__ timW, const float* __restrict__ globW,
    bf16_t* __restrict__ bst2, bf16_t* __restrict__ wdT,
    bf16_t* __restrict__ timT, bf16_t* __restrict__ globT){
  int z = blockIdx.z;
  const float* in; const float* in2 = nullptr; bf16_t* outp; int ldout;
  switch(z){
    case 0: in = Wn;           outp = bst2;                       ldout = 512; break;
    case 1: in = Wl;           outp = bst2 + 256;                 ldout = 512; break;
    case 2: in = Wn + 65536;   outp = bst2 + (size_t)256*512;     ldout = 512; break;
    case 3: in = Wl + 65536;   outp = bst2 + (size_t)256*512+256; ldout = 512; break;
    case 4: in = We;          in2 = Wl;         outp = wdT;         ldout = 256; break;
    case 5: in = We + 65536;  in2 = Wl + 65536; outp = wdT + 65536; ldout = 256; break;
    case 6: in = timW;  outp = timT;  ldout = 256; break;
    default:in = globW; outp = globT; ldout = 256; break;
  }
  __shared__ float tile[32][33];
  int n0 = blockIdx.x*32, k0 = blockIdx.y*32;
  int tx = threadIdx.x & 31, ty = threadIdx.x >> 5;
  #pragma unroll
  for (int j=0;j<4;j++){
    size_t idx = (size_t)(k0+ty+j*8)*256 + n0+tx;
    float v = in[idx];
    if (in2) v -= in2[idx];
    tile[ty+j*8][tx] = v;
  }
  __syncthreads();
  #pragma unroll
  for (int j=0;j<4;j++)
    outp[(size_t)(n0+ty+j*8)*ldout + k0+tx] = (bf16_t)tile[tx][ty+j*8];
}

// ---------------- merged row copy+convert jobs via blockIdx.y ----------------
__global__ __launch_bounds__(256) void copyall_k(const float* __restrict__ gW_ih,
    const float* __restrict__ gW_hh, const float* __restrict__ W_hp, const float* __restrict__ emb_rel,
    bf16_t* __restrict__ wihAT, bf16_t* __restrict__ wihBT, bf16_t* __restrict__ whhT,
    bf16_t* __restrict__ whpT, bf16_t* __restrict__ h0b){
  int r = blockIdx.x, c = threadIdx.x, y = blockIdx.y;
  if (y == 0)      wihAT[(size_t)r*256+c] = (bf16_t)gW_ih[(size_t)r*512 + c];
  else if (y == 1) wihBT[(size_t)r*256+c] = (bf16_t)gW_ih[(size_t)r*512 + 256 + c];
  else if (y == 2) whhT[(size_t)r*256+c]  = (bf16_t)gW_hh[(size_t)r*256 + c];
  else if (y == 3){ if (r < 256) whpT[(size_t)r*256+c] = (bf16_t)W_hp[(size_t)r*259 + c]; }
  else            { if (r < RR)  h0b[(size_t)r*256+c]  = (bf16_t)emb_rel[(size_t)r*256 + c]; }
}

// ---------------- misc small setup: WP extract + b_ov ----------------
__global__ __launch_bounds__(256) void misc_k(const float* __restrict__ W_hp, float* __restrict__ WP,
    const float* __restrict__ W_o, const float* __restrict__ b_v, const float* __restrict__ b_o,
    float* __restrict__ b_ov){
  if (blockIdx.x == 0){
    int j = threadIdx.x;
    #pragma unroll
    for (int p=0;p<PP;p++) WP[p*HH + j] = W_hp[(size_t)j*259 + HH + p];
  } else {
    int n = threadIdx.x;
    float s = b_o[n];
    for (int j=0;j<256;j++) s += W_o[(size_t)n*256+j]*b_v[j];
    b_ov[n] = s;
  }
}

// ---------------- row copy+convert (wovT after sgemm) ----------------
__global__ __launch_bounds__(256) void copy_bfw_k(const float* __restrict__ in, bf16_t* __restrict__ outp){
  int r = blockIdx.x, c = threadIdx.x;
  outp[(size_t)r*HH + c] = (bf16_t)in[(size_t)r*HH + c];
}

// ---------------- f32 SGEMM (setup: WovF only) ----------------
__global__ __launch_bounds__(256) void sgemm_k(const float* __restrict__ A, const float* __restrict__ B,
                                               float* __restrict__ C, int M, int N, int K){
  __shared__ float As[16][128];
  __shared__ float Bs[16][64];
  int tid = threadIdx.x;
  int tx = tid & 15, ty = tid >> 4;
  int rowBase = blockIdx.x * 128;
  int colBase = blockIdx.y * 64;
  float acc[8][4];
  #pragma unroll
  for (int i=0;i<8;i++)
    #pragma unroll
    for (int j=0;j<4;j++) acc[i][j]=0.f;
  for (int k0=0;k0<K;k0+=16){
    #pragma unroll
    for (int ss=0; ss<2; ss++){
      int s = tid + ss*256;
      int r = s >> 2;
      int kk = (s & 3)*4;
      float4 v = make_float4(0.f,0.f,0.f,0.f);
      int grow = rowBase + r;
      if (grow < M) v = *(const float4*)(A + (size_t)grow*K + k0 + kk);
      As[kk+0][r]=v.x; As[kk+1][r]=v.y; As[kk+2][r]=v.z; As[kk+3][r]=v.w;
    }
    {
      int r = tid >> 4, cc = (tid & 15)*4;
      float4 v = *(const float4*)(B + (size_t)(k0+r)*N + colBase + cc);
      *(float4*)&Bs[r][cc] = v;
    }
    __syncthreads();
    #pragma unroll
    for (int kk=0;kk<16;kk++){
      float a[8], b[4];
      *(float4*)&a[0] = *(const float4*)&As[kk][ty*8];
      *(float4*)&a[4] = *(const float4*)&As[kk][ty*8+4];
      *(float4*)&b[0] = *(const float4*)&Bs[kk][tx*4];
      #pragma unroll
      for (int i=0;i<8;i++)
        #pragma unroll
        for (int j=0;j<4;j++)
          acc[i][j] = fmaf(a[i], b[j], acc[i][j]);
    }
    __syncthreads();
  }
  #pragma unroll
  for (int i=0;i<8;i++){
    int gr = rowBase + ty*8 + i;
    if (gr >= M) continue;
    float4 v = make_float4(acc[i][0], acc[i][1], acc[i][2], acc[i][3]);
    *(float4*)(C + (size_t)gr*N + colBase + tx*4) = v;
  }
}

// ---------------- bf16 MFMA GEMM (BM=BN=128, BK=64, 4 waves 2x2), fused epilogues ----------------
// C[M][N] = A[M][K] @ Bt[N][K]^T.
// SPLITA: K=512, k<256 from A0, k>=256 from A1 (both stride 256).
// EPI: 0 plain(+bias); 2 tanh(v+pos+bias) [e1=pos, e2=WP]; 3 gate-blend: g=sigm(v+bias),
//      C=g*eb+(1-g)*eb2 (both bf16); 4 deg-aware leaky; 5 deg0 fix (rows via z, v=leaky(Cb_raw+v));
//      7 sigm(v+bias)->bf16; 8 v += e1-matrix.
template<int EPI, int WF32, int WBF, int HASB, int SPLITA>
__global__ __launch_bounds__(256) void mgemm_k(
    const bf16_t* __restrict__ A0, const bf16_t* __restrict__ A1,
    const bf16_t* __restrict__ Bt,
    float* __restrict__ C, bf16_t* __restrict__ Cb, const float* __restrict__ bias,
    int M, int N, int K,
    const float* __restrict__ e1, const float* __restrict__ e2,
    const bf16_t* __restrict__ eb, const bf16_t* __restrict__ eb2,
    const int* __restrict__ degp, const int* __restrict__ z, const int* __restrict__ nzp){
  int rowBase = blockIdx.x * 128;
  int nzv = 0;
  if (EPI == 5){
    nzv = nzp[0];
    if (rowBase >= nzv) return;
  }
  __shared__ bf16_t As[128*64];
  __shared__ bf16_t Bs[128*64];
  int tid = threadIdx.x;
  int lane = tid & 63, w = tid >> 6;
  int wm = w >> 1, wn = w & 1;
  int colBase = blockIdx.y * 128;
  f32x4 acc[4][4] = {};

  int lrow = lane >> 3;          // 0..7 within the wave's 8-row group
  int p    = lane & 7;           // phys 16B seg
  int arow[4];
  #pragma unroll
  for (int c = 0; c < 4; c++){
    int gr = rowBase + c*32 + w*8 + lrow;
    if (EPI == 5) arow[c] = z[min(gr, nzv-1)];
    else          arow[c] = min(gr, M-1);
  }
  for (int k0 = 0; k0 < K; k0 += 64){
    const bf16_t* Ap; int koff; size_t lda;
    if (SPLITA){ Ap = (k0 < 256) ? A0 : A1; koff = k0 & 255; lda = 256; }
    else       { Ap = A0; koff = k0; lda = (size_t)K; }
    #pragma unroll
    for (int c = 0; c < 4; c++){
      int r = c*32 + w*8 + lrow;
      int s = p ^ (r & 7);                     // both-sides swizzle
      gload_lds16(Ap + (size_t)arow[c]*lda + koff + s*8, As + (size_t)(c*32 + w*8)*64);
      int gb = colBase + r;                    // N multiple of 128 always
      gload_lds16(Bt + (size_t)gb*K + k0 + s*8, Bs + (size_t)(c*32 + w*8)*64);
    }
    asm volatile("s_waitcnt vmcnt(0)" ::: "memory");
    __syncthreads();
    #pragma unroll
    for (int kk = 0; kk < 2; kk++){
      bf16x8 af[4], bfr[4];
      int sg = kk*4 + (lane >> 4);             // logical seg 0..7
      #pragma unroll
      for (int i = 0; i < 4; i++){
        int r = wm*64 + i*16 + (lane & 15);
        af[i] = *(const bf16x8*)(As + r*64 + (sg ^ (r & 7))*8);
      }
      #pragma unroll
      for (int j = 0; j < 4; j++){
        int rn = wn*64 + j*16 + (lane & 15);
        bfr[j] = *(const bf16x8*)(Bs + rn*64 + (sg ^ (rn & 7))*8);
      }
      #pragma unroll
      for (int i = 0; i < 4; i++)
        #pragma unroll
        for (int j = 0; j < 4; j++)
          acc[i][j] = __builtin_amdgcn_mfma_f32_16x16x32_bf16(af[i], bfr[j], acc[i][j], 0, 0, 0);
    }
    __syncthreads();
  }
  // ---- epilogue ----
  int colv[4]; float bb[4], wp0[4], wp1[4], wp2[4];
  #pragma unroll
  for (int j = 0; j < 4; j++){
    colv[j] = colBase + wn*64 + j*16 + (lane & 15);
    bb[j] = HASB ? bias[colv[j]] : 0.f;
    if (EPI == 2){ wp0[j] = e2[colv[j]]; wp1[j] = e2[256+colv[j]]; wp2[j] = e2[512+colv[j]]; }
  }
  #pragma unroll
  for (int i = 0; i < 4; i++){
    #pragma unroll
    for (int q = 0; q < 4; q++){
      int grt = rowBase + wm*64 + i*16 + ((lane >> 4) << 2) + q;
      if (EPI == 5){ if (grt >= nzv) continue; }
      else         { if (grt >= M) continue; }
      int orow = (EPI == 5) ? z[grt] : grt;
      int dflag = 0;
      if (EPI == 4) dflag = degp[orow];
      float p0=0.f, p1=0.f, p2=0.f;
      if (EPI == 2){ p0 = e1[(size_t)grt*3]; p1 = e1[(size_t)grt*3+1]; p2 = e1[(size_t)grt*3+2]; }
      #pragma unroll
      for (int j = 0; j < 4; j++){
        size_t idx = (size_t)orow*N + colv[j];
        float v = acc[i][j][q] + bb[j];
        if (EPI == 2) v = tanhf(v + p0*wp0[j] + p1*wp1[j] + p2*wp2[j]);
        if (EPI == 3){
          float g = sigm(v);
          v = g*(float)eb[idx] + (1.f-g)*(float)eb2[idx];
        }
        if (EPI == 4) v = (dflag > 0) ? leaky(v) : v;
        if (EPI == 5){
          float praw = (float)Cb[idx];
          v = leaky(praw + v);
        }
        if (EPI == 7) v = sigm(v);
        if (EPI == 8) v += e1[idx];
        if (WF32) C[idx] = v;
        if (WBF)  Cb[idx] = (bf16_t)v;
      }
    }
  }
}

// ---------------- row-wise L2 normalize -> bf16 (setup) ----------------
__global__ __launch_bounds__(256) void l2norm_k(const float* __restrict__ in, bf16_t* __restrict__ outb){
  int i = blockIdx.x, c = threadIdx.x;
  size_t idx = (size_t)i*HH + c;
  float v = in[idx];
  float ss = v*v;
  #pragma unroll
  for (int o=32;o;o>>=1) ss += __shfl_down(ss, o);
  __shared__ float red[4];
  if ((threadIdx.x & 63)==0) red[threadIdx.x>>6] = ss;
  __syncthreads();
  float tot = red[0]+red[1]+red[2]+red[3];
  outb[idx] = (bf16_t)(v / fmaxf(sqrtf(tot), 1e-12f));
}

// ---------------- batched combined histogram over all 3 t's ----------------
__global__ __launch_bounds__(256) void hist3_k(const int* __restrict__ r_seg, const int* __restrict__ dst,
                                               int* __restrict__ cnt){
  int q = blockIdx.x*256 + threadIdx.x;
  if (q >= 3*2*EE) return;
  int t = q / (2*EE);
  int e = q - t*2*EE;
  if (e < EE) atomicAdd(cnt + t*NBIN + r_seg[(size_t)t*EE + e], 1);
  else        atomicAdd(cnt + t*NBIN + RR + dst[(size_t)t*EE + (e-EE)], 1);
}

// ---------------- hierarchical exclusive scan ----------------
__global__ __launch_bounds__(1024) void scan1_k(const int* __restrict__ cnt, int* __restrict__ start,
                                                int* __restrict__ bsum, int n){
  __shared__ int s[1024];
  int t = blockIdx.x*1024 + threadIdx.x;
  int v = (t < n) ? cnt[t] : 0;
  s[threadIdx.x] = v;
  __syncthreads();
  for (int off = 1; off < 1024; off <<= 1){
    int x = (threadIdx.x >= off) ? s[threadIdx.x - off] : 0;
    __syncthreads();
    s[threadIdx.x] += x;
    __syncthreads();
  }
  if (t < n) start[t] = s[threadIdx.x] - v;
  if (threadIdx.x == 1023) bsum[blockIdx.x] = s[1023];
}
__global__ __launch_bounds__(256) void scan2_k(const int* __restrict__ bsum, int* __restrict__ boff,
                                               int* __restrict__ start, int nb, int n){
  __shared__ int s[256];
  int t = threadIdx.x;
  int v = (t < nb) ? bsum[t] : 0;
  s[t] = v;
  __syncthreads();
  for (int off = 1; off < 256; off <<= 1){
    int x = (t >= off) ? s[t-off] : 0;
    __syncthreads();
    s[t] += x;
    __syncthreads();
  }
  if (t < nb) boff[t] = s[t] - v;
  if (t == 255) start[n] = s[255];
}
__global__ __launch_bounds__(1024) void scan3_k(int* __restrict__ start, int* __restrict__ cur,
                                                const int* __restrict__ boff, int n){
  int t = blockIdx.x*1024 + threadIdx.x;
  if (t < n){
    int v = start[t] + boff[blockIdx.x];
    start[t] = v;
    cur[t] = v;
  }
}

// ---------------- batched CSR fill (dst side packs src|ety<<16 into u32) ----------------
__global__ __launch_bounds__(256) void fill3_k(const int* __restrict__ r_seg, const int* __restrict__ r_to_e,
    const int* __restrict__ dst, const int* __restrict__ src, const int* __restrict__ ety,
    int* __restrict__ cur, int* __restrict__ rnode, unsigned* __restrict__ dpack){
  int q = blockIdx.x*256 + threadIdx.x;
  if (q >= 3*2*EE) return;
  int t = q / (2*EE);
  int e = q - t*2*EE;
  if (e < EE){
    size_t ge = (size_t)t*EE + e;
    int pp = atomicAdd(cur + t*NBIN + r_seg[ge], 1);
    rnode[pp - EE*t] = r_to_e[ge];
  } else {
    size_t ge = (size_t)t*EE + (e - EE);
    int pp = atomicAdd(cur + t*NBIN + RR + dst[ge], 1);
    dpack[pp - EE*(t+1)] = (unsigned)src[ge] | ((unsigned)ety[ge] << 16);
  }
}

// ---------------- batched compact deg-0 node lists (wave-aggregated atomics) ----------------
__global__ __launch_bounds__(256) void compact3_k(const int* __restrict__ cnt, int* __restrict__ zAll,
                                                  int* __restrict__ nz){
  int q = blockIdx.x*256 + threadIdx.x;
  int lane = threadIdx.x & 63;
  bool valid = q < 3*NN;
  int qc = valid ? q : 3*NN - 1;
  int t = qc / NN, d = qc - t*NN;
  bool pred = valid && (cnt[t*NBIN + RR + d] == 0);
  int tA = __shfl(t, 0), tB = __shfl(t, 63);
  if (tA == tB){
    unsigned long long m = __ballot(pred);
    int total = __popcll(m);
    int base = 0;
    if (lane == 0 && total > 0) base = atomicAdd(nz + tA, total);
    base = __shfl(base, 0);
    if (pred){
      int myoff = __popcll(m & ((1ULL << lane) - 1ULL));
      zAll[(size_t)tA*NN + base + myoff] = d;
    }
  } else {
    if (pred){
      int pp = atomicAdd(nz + t, 1);
      zAll[(size_t)t*NN + pp] = d;
    }
  }
}

// per-relation mean of h rows (bf16 out)
__global__ __launch_bounds__(256) void rmean_k(const int* __restrict__ startT, const int* __restrict__ rnode,
    const bf16_t* __restrict__ hb, bf16_t* __restrict__ meanb, int rbase){
  int r = blockIdx.x, c = threadIdx.x;
  int s0 = startT[r] - rbase, s1 = startT[r+1] - rbase;
  float acc = 0.f, acc2 = 0.f;
  int i = s0;
  for (; i + 1 < s1; i += 2){
    acc  += (float)hb[(size_t)rnode[i]*HH + c];
    acc2 += (float)hb[(size_t)rnode[i+1]*HH + c];
  }
  if (i < s1) acc += (float)hb[(size_t)rnode[i]*HH + c];
  acc += acc2;
  int cnt = s1 - s0;
  meanb[(size_t)r*HH + c] = (bf16_t)((cnt > 0) ? acc/(float)cnt : 0.f);
}

// ---------------- GRU gates + row l2norm, in-place h0 (f32) + bf16 shadow ----------------
__global__ __launch_bounds__(256) void gru_gate_k(const float* __restrict__ gi,
    const float* __restrict__ ghb, float* __restrict__ h0, bf16_t* __restrict__ h0b){
  int r = blockIdx.x, c = threadIdx.x;
  float ir = gi[(size_t)r*768 + c],       hr = ghb[(size_t)r*768 + c];
  float iz = gi[(size_t)r*768 + 256 + c], hz = ghb[(size_t)r*768 + 256 + c];
  float in_ = gi[(size_t)r*768 + 512 + c], hn = ghb[(size_t)r*768 + 512 + c];
  float rg = sigm(ir + hr);
  float z  = sigm(iz + hz);
  float n  = tanhf(in_ + rg*hn);
  float hp = h0[(size_t)r*HH + c];
  float v = (1.f - z)*n + z*hp;
  float ss = v*v;
  #pragma unroll
  for (int o=32;o;o>>=1) ss += __shfl_down(ss, o);
  __shared__ float red[4];
  if ((threadIdx.x & 63)==0) red[threadIdx.x>>6] = ss;
  __syncthreads();
  float tot = red[0]+red[1]+red[2]+red[3];
  float nv = v / fmaxf(sqrtf(tot), 1e-12f);
  h0[(size_t)r*HH + c] = nv;
  h0b[(size_t)r*HH + c] = (bf16_t)nv;
}

// ---------------- gather mean messages (packed u32 edge payload) ----------------
__global__ __launch_bounds__(256) void gatherM_k(const bf16_t* __restrict__ nin,
    const bf16_t* __restrict__ h0b, const int* __restrict__ startT,
    const unsigned* __restrict__ dpack, bf16_t* __restrict__ Amean, int ebase){
  int w = threadIdx.x >> 6, ln = threadIdx.x & 63;
  int d = blockIdx.x*4 + w;
  if (d >= NN) return;
  int s0 = startT[RR + d] - ebase, s1 = startT[RR + d + 1] - ebase;
  int deg = s1 - s0;
  float a0=0.f, a1=0.f, a2=0.f, a3=0.f;
  for (int i = s0; i < s1; i++){
    unsigned se = dpack[i];
    int s = (int)(se & 0xffffu);
    int r = (int)(se >> 16);
    uint2 ra = *(const uint2*)(nin + (size_t)s*HH + ln*4);
    uint2 rb = *(const uint2*)(h0b + (size_t)r*HH + ln*4);
    a0 += __uint_as_float((ra.x & 0xffffu) << 16) + __uint_as_float((rb.x & 0xffffu) << 16);
    a1 += __uint_as_float(ra.x & 0xffff0000u)     + __uint_as_float(rb.x & 0xffff0000u);
    a2 += __uint_as_float((ra.y & 0xffffu) << 16) + __uint_as_float((rb.y & 0xffffu) << 16);
    a3 += __uint_as_float(ra.y & 0xffff0000u)     + __uint_as_float(rb.y & 0xffff0000u);
  }
  float inv = (deg > 0) ? 1.f/(float)deg : 0.f;
  bf16_t m[4] = { (bf16_t)(a0*inv), (bf16_t)(a1*inv), (bf16_t)(a2*inv), (bf16_t)(a3*inv) };
  *(uint2*)(Amean + (size_t)d*HH + ln*4) = *(const uint2*)m;
}

// ---------------- fused l2norm(nh2_bf) + time-gate h update (bf16 state, in-place, same-thread) ----------------
__global__ __launch_bounds__(256) void l2up_k(const bf16_t* __restrict__ nh2b, const bf16_t* __restrict__ sg,
    bf16_t* __restrict__ hb){
  int i = blockIdx.x, c = threadIdx.x;
  size_t idx = (size_t)i*HH + c;
  float v = (float)nh2b[idx];
  float ss = v*v;
  #pragma unroll
  for (int o=32;o;o>>=1) ss += __shfl_down(ss, o);
  __shared__ float red[4];
  if ((threadIdx.x & 63)==0) red[threadIdx.x>>6] = ss;
  __syncthreads();
  float tot = red[0]+red[1]+red[2]+red[3];
  float curn = v / fmaxf(sqrtf(tot), 1e-12f);
  float s = (float)sg[idx];
  float hn = s*curn + (1.f-s)*(float)hb[idx];
  hb[idx] = (bf16_t)hn;
}

extern "C" void kernel_launch(void* const* d_in, const int* in_sizes, int n_in,
                              void* d_out, int out_size, void* d_ws, size_t ws_size,
                              hipStream_t stream) {
  const int*   src     = (const int*)  d_in[0];
  const int*   dst     = (const int*)  d_in[1];
  const int*   etype   = (const int*)  d_in[2];
  const int*   r_to_e  = (const int*)  d_in[3];
  const int*   r_seg   = (const int*)  d_in[4];
  const float* pos_enc = (const float*)d_in[5];
  const float* dyn_emb = (const float*)d_in[6];
  const float* emb_rel = (const float*)d_in[7];
  const float* gW_ih   = (const float*)d_in[8];
  const float* gW_hh   = (const float*)d_in[9];
  const float* gb_ih   = (const float*)d_in[10];
  const float* gb_hh   = (const float*)d_in[11];
  const float* W_neigh = (const float*)d_in[12];
  const float* W_loop  = (const float*)d_in[13];
  const float* W_evolve= (const float*)d_in[14];
  const float* W_hp    = (const float*)d_in[15];
  const float* b_hp    = (const float*)d_in[16];
  const float* W_v     = (const float*)d_in[17];
  const float* b_v     = (const float*)d_in[18];
  const float* W_o     = (const float*)d_in[19];
  const float* b_o     = (const float*)d_in[20];
  const float* time_W  = (const float*)d_in[21];
  const float* time_b  = (const float*)d_in[22];
  const float* glob_W  = (const float*)d_in[23];
  const float* glob_b  = (const float*)d_in[24];
  float* out = (float*)d_out;
  (void)in_sizes; (void)n_in; (void)out_size; (void)ws_size;

  char* ws = (char*)d_ws;
  size_t off = 0;
  auto allocB = [&](size_t bytes)->char*{
    char* pp = ws + off; off += (bytes + 255) & ~(size_t)255;
    return pp;
  };
  float*  tmp    = (float*) allocB(NHf*4);          // Amean (bf16, 1st half) + sgate (bf16, 2nd half)
  bf16_t* h_bf   = (bf16_t*)allocB(NHf*2);          // recurrent state (bf16)
  bf16_t* nh_bf  = (bf16_t*)allocB(NHf*2);          // layer-0 out; aliased: attn_bf
  bf16_t* nh2_bf = (bf16_t*)allocB(NHf*2);
  bf16_t* gh_bf  = (bf16_t*)allocB(NHf*2);
  bf16_t* Amean  = (bf16_t*)tmp;
  bf16_t* sgate  = (bf16_t*)(tmp + NHf/2);
  bf16_t* attn_bf= nh_bf;

  float*  h0    = (float*) allocB((size_t)RR*HH*4);
  bf16_t* h0b   = (bf16_t*)allocB((size_t)RR*HH*2);
  bf16_t* meanb = (bf16_t*)allocB((size_t)RR*HH*2);
  float*  gi0   = (float*) allocB((size_t)RR*768*4);
  float*  gi    = (float*) allocB((size_t)RR*768*4);
  float*  ghb   = (float*) allocB((size_t)RR*768*4);
  bf16_t* wihAT = (bf16_t*)allocB((size_t)768*256*2);
  bf16_t* wihBT = (bf16_t*)allocB((size_t)768*256*2);
  bf16_t* whhT  = (bf16_t*)allocB((size_t)768*256*2);
  float*  WP    = (float*) allocB((size_t)PP*HH*4);
  float*  WovF  = (float*) allocB((size_t)HH*HH*4);
  float*  b_ov  = (float*) allocB((size_t)HH*4);
  bf16_t* bst2  = (bf16_t*)allocB((size_t)2*HH*512*2);   // per-layer [Wn|Wl]^T, ld 512
  bf16_t* wdT   = (bf16_t*)allocB((size_t)2*HH*HH*2);    // per-layer (We-Wl)^T
  bf16_t* whpT  = (bf16_t*)allocB((size_t)HH*HH*2);
  bf16_t* wovT  = (bf16_t*)allocB((size_t)HH*HH*2);
  bf16_t* timT  = (bf16_t*)allocB((size_t)HH*HH*2);
  bf16_t* globT = (bf16_t*)allocB((size_t)HH*HH*2);
  int* cnt    = (int*)allocB((size_t)(NBIN3+4)*4);       // + nz[3] at tail
  int* start  = (int*)allocB((size_t)(NBIN3+1)*4);
  int* cur    = (int*)allocB((size_t)NBIN3*4);
  int* rnode  = (int*)allocB((size_t)3*EE*4);
  unsigned* dpack = (unsigned*)allocB((size_t)3*EE*4);
  int* zAll   = (int*)allocB((size_t)3*NN*4);
  int* bsum   = (int*)allocB(256*4);
  int* boff   = (int*)allocB(256*4);
  int* nz     = cnt + NBIN3;

  const int MT  = (NN + 127)/128;            // 391 row tiles
  const int NB3 = (NBIN3 + 1023)/1024;       // 148 scan blocks

  // ---- setup: weight prep + initial h/h0 + gi0 ----
  copyall_k<<<dim3(768,5), 256, 0, stream>>>(gW_ih, gW_hh, W_hp, emb_rel,
                                             wihAT, wihBT, whhT, whpT, h0b);
  tconv_all_k<<<dim3(8,8,8), 256, 0, stream>>>(W_neigh, W_loop, W_evolve, time_W, glob_W,
                                               bst2, wdT, timT, globT);
  misc_k<<<2, 256, 0, stream>>>(W_hp, WP, W_o, b_v, b_o, b_ov);
  sgemm_k<<<dim3(2,4), 256, 0, stream>>>(W_o, W_v, WovF, 256, 256, 256);
  copy_bfw_k<<<HH, 256, 0, stream>>>(WovF, wovT);
  l2norm_k<<<NN, 256, 0, stream>>>(dyn_emb, h_bf);
  hipMemcpyAsync(h0, emb_rel, (size_t)RR*HH*4, hipMemcpyDeviceToDevice, stream);
  // gi0 = emb_rel @ W_ih[:, :256]^T + b_ih   (h0b == emb_rel bf16 at this point)
  mgemm_k<0,1,0,1,0><<<dim3(4,6), 256, 0, stream>>>(h0b, nullptr, wihAT, gi0, nullptr, gb_ih,
      RR, 768, 256, nullptr, nullptr, nullptr, nullptr, nullptr, nullptr, nullptr);

  // ---- batched CSR build for all 3 snapshots ----
  hipMemsetAsync(cnt, 0, (size_t)(NBIN3+4)*4, stream);
  hist3_k<<<(6*EE+255)/256, 256, 0, stream>>>(r_seg, dst, cnt);
  scan1_k<<<NB3, 1024, 0, stream>>>(cnt, start, bsum, NBIN3);
  scan2_k<<<1, 256, 0, stream>>>(bsum, boff, start, NB3, NBIN3);
  scan3_k<<<NB3, 1024, 0, stream>>>(start, cur, boff, NBIN3);
  fill3_k<<<(6*EE+255)/256, 256, 0, stream>>>(r_seg, r_to_e, dst, src, etype, cur, rnode, dpack);
  compact3_k<<<(3*NN+255)/256, 256, 0, stream>>>(cnt, zAll, nz);

  for (int t=0; t<TT; t++){
    const float* posT = pos_enc + (size_t)t*NN*PP;
    const int* startT = start + (size_t)t*NBIN;
    const int* degT   = cnt + (size_t)t*NBIN + RR;
    const int* zT     = zAll + (size_t)t*NN;
    const int* nzT    = nz + t;

    // ---- relation mean + GRU ----
    rmean_k<<<RR, 256, 0, stream>>>(startT, rnode, h_bf, meanb, EE*t);
    mgemm_k<8,1,0,0,0><<<dim3(4,6), 256, 0, stream>>>(meanb, nullptr, wihBT, gi, nullptr, nullptr,
        RR, 768, 256, gi0, nullptr, nullptr, nullptr, nullptr, nullptr, nullptr);
    mgemm_k<0,1,0,1,0><<<dim3(4,6), 256, 0, stream>>>(h0b, nullptr, whhT, ghb, nullptr, gb_hh,
        RR, 768, 256, nullptr, nullptr, nullptr, nullptr, nullptr, nullptr, nullptr);
    gru_gate_k<<<RR, 256, 0, stream>>>(gi, ghb, h0, h0b);

    // ---- RGCN layer 0 ----
    gatherM_k<<<(NN+3)/4, 256, 0, stream>>>(h_bf, h0b, startT, dpack, Amean, EE*(t+1));
    mgemm_k<4,0,1,0,1><<<dim3(MT,2), 256, 0, stream>>>(Amean, h_bf, bst2, nullptr, nh_bf, nullptr,
        NN, 256, 512, nullptr, nullptr, nullptr, nullptr, degT, nullptr, nullptr);
    mgemm_k<5,0,1,0,0><<<dim3(MT,2), 256, 0, stream>>>(h_bf, nullptr, wdT, nullptr, nh_bf, nullptr,
        NN, 256, 256, nullptr, nullptr, nullptr, nullptr, nullptr, zT, nzT);

    // ---- RGCN layer 1 ----
    gatherM_k<<<(NN+3)/4, 256, 0, stream>>>(nh_bf, h0b, startT, dpack, Amean, EE*(t+1));
    mgemm_k<4,0,1,0,1><<<dim3(MT,2), 256, 0, stream>>>(Amean, nh_bf, bst2 + (size_t)HH*512, nullptr, nh2_bf, nullptr,
        NN, 256, 512, nullptr, nullptr, nullptr, nullptr, degT, nullptr, nullptr);
    mgemm_k<5,0,1,0,0><<<dim3(MT,2), 256, 0, stream>>>(nh_bf, nullptr, wdT + (size_t)HH*HH, nullptr, nh2_bf, nullptr,
        NN, 256, 256, nullptr, nullptr, nullptr, nullptr, nullptr, zT, nzT);

    // ---- attention chain ----
    mgemm_k<2,0,1,1,0><<<dim3(MT,2), 256, 0, stream>>>(nh2_bf, nullptr, whpT, nullptr, attn_bf, b_hp,
        NN, 256, 256, posT, WP, nullptr, nullptr, nullptr, nullptr, nullptr);
    mgemm_k<0,0,1,1,0><<<dim3(MT,2), 256, 0, stream>>>(attn_bf, nullptr, wovT, nullptr, gh_bf, b_ov,
        NN, 256, 256, nullptr, nullptr, nullptr, nullptr, nullptr, nullptr, nullptr);

    // ---- time gate (sigmoid in epilogue, bf16), fused norm+update (in-place bf16 h), glob+blend ----
    mgemm_k<7,0,1,1,0><<<dim3(MT,2), 256, 0, stream>>>(h_bf, nullptr, timT, nullptr, sgate, time_b,
        NN, 256, 256, nullptr, nullptr, nullptr, nullptr, nullptr, nullptr, nullptr);
    l2up_k<<<NN, 256, 0, stream>>>(nh2_bf, sgate, h_bf);
    mgemm_k<3,1,0,1,0><<<dim3(MT,2), 256, 0, stream>>>(h_bf, nullptr, globT, out + (size_t)t*NHf, nullptr, glob_b,
        NN, 256, 256, nullptr, nullptr, gh_bf, h_bf, nullptr, nullptr, nullptr);
  }
}

// Round 12
// 1370.039 us; speedup vs baseline: 1.1985x; 1.1410x over previous
//
#include <hip/hip_runtime.h>
#include <math.h>

#define NN 50000
#define HH 256
#define RR 460
#define TT 3
#define EE 100000
#define PP 3
#define SLOPE 0.22916666666666666f
#define NBIN (RR + NN)           // per-t bins: 50460
#define NBIN3 (3*NBIN)           // batched bins

typedef __bf16 bf16_t;
typedef bf16_t bf16x8 __attribute__((ext_vector_type(8)));
typedef float f32x4 __attribute__((ext_vector_type(4)));

static const size_t NHf = (size_t)NN * HH;   // 12.8M elements

__device__ __forceinline__ float sigm(float x){ return 1.0f/(1.0f+__expf(-x)); }
__device__ __forceinline__ float leaky(float x){ return (x >= 0.f) ? x : SLOPE*x; }

__device__ __forceinline__ void gload_lds16(const void* g, void* l){
  __builtin_amdgcn_global_load_lds((const __attribute__((address_space(1))) void*)g,
                                   (__attribute__((address_space(3))) void*)l, 16, 0, 0);
}

// ---------------- merged weight transposes (sub fused for Wd): 8 jobs via blockIdx.z ----------------
__global__ __launch_bounds__(256) void tconv_all_k(
    const float* __restrict__ Wn, const float* __restrict__ Wl, const float* __restrict__ We,
    const float* __restrict__ timW, const float* __restrict__ globW,
    bf16_t* __restrict__ bst2, bf16_t* __restrict__ wdT,
    bf16_t* __restrict__ timT, bf16_t* __restrict__ globT){
  int z = blockIdx.z;
  const float* in; const float* in2 = nullptr; bf16_t* outp; int ldout;
  switch(z){
    case 0: in = Wn;           outp = bst2;                       ldout = 512; break;
    case 1: in = Wl;           outp = bst2 + 256;                 ldout = 512; break;
    case 2: in = Wn + 65536;   outp = bst2 + (size_t)256*512;     ldout = 512; break;
    case 3: in = Wl + 65536;   outp = bst2 + (size_t)256*512+256; ldout = 512; break;
    case 4: in = We;          in2 = Wl;         outp = wdT;         ldout = 256; break;
    case 5: in = We + 65536;  in2 = Wl + 65536; outp = wdT + 65536; ldout = 256; break;
    case 6: in = timW;  outp = timT;  ldout = 256; break;
    default:in = globW; outp = globT; ldout = 256; break;
  }
  __shared__ float tile[32][33];
  int n0 = blockIdx.x*32, k0 = blockIdx.y*32;
  int tx = threadIdx.x & 31, ty = threadIdx.x >> 5;
  #pragma unroll
  for (int j=0;j<4;j++){
    size_t idx = (size_t)(k0+ty+j*8)*256 + n0+tx;
    float v = in[idx];
    if (in2) v -= in2[idx];
    tile[ty+j*8][tx] = v;
  }
  __syncthreads();
  #pragma unroll
  for (int j=0;j<4;j++)
    outp[(size_t)(n0+ty+j*8)*ldout + k0+tx] = (bf16_t)tile[tx][ty+j*8];
}

// ---------------- merged row copy+convert jobs via blockIdx.y ----------------
__global__ __launch_bounds__(256) void copyall_k(const float* __restrict__ gW_ih,
    const float* __restrict__ gW_hh, const float* __restrict__ W_hp, const float* __restrict__ emb_rel,
    bf16_t* __restrict__ wihAT, bf16_t* __restrict__ wihBT, bf16_t* __restrict__ whhT,
    bf16_t* __restrict__ whpT, bf16_t* __restrict__ h0b){
  int r = blockIdx.x, c = threadIdx.x, y = blockIdx.y;
  if (y == 0)      wihAT[(size_t)r*256+c] = (bf16_t)gW_ih[(size_t)r*512 + c];
  else if (y == 1) wihBT[(size_t)r*256+c] = (bf16_t)gW_ih[(size_t)r*512 + 256 + c];
  else if (y == 2) whhT[(size_t)r*256+c]  = (bf16_t)gW_hh[(size_t)r*256 + c];
  else if (y == 3){ if (r < 256) whpT[(size_t)r*256+c] = (bf16_t)W_hp[(size_t)r*259 + c]; }
  else            { if (r < RR)  h0b[(size_t)r*256+c]  = (bf16_t)emb_rel[(size_t)r*256 + c]; }
}

// ---------------- misc small setup: WP extract + b_ov ----------------
__global__ __launch_bounds__(256) void misc_k(const float* __restrict__ W_hp, float* __restrict__ WP,
    const float* __restrict__ W_o, const float* __restrict__ b_v, const float* __restrict__ b_o,
    float* __restrict__ b_ov){
  if (blockIdx.x == 0){
    int j = threadIdx.x;
    #pragma unroll
    for (int p=0;p<PP;p++) WP[p*HH + j] = W_hp[(size_t)j*259 + HH + p];
  } else {
    int n = threadIdx.x;
    float s = b_o[n];
    for (int j=0;j<256;j++) s += W_o[(size_t)n*256+j]*b_v[j];
    b_ov[n] = s;
  }
}

// ---------------- row copy+convert (wovT after sgemm) ----------------
__global__ __launch_bounds__(256) void copy_bfw_k(const float* __restrict__ in, bf16_t* __restrict__ outp){
  int r = blockIdx.x, c = threadIdx.x;
  outp[(size_t)r*HH + c] = (bf16_t)in[(size_t)r*HH + c];
}

// ---------------- f32 SGEMM (setup: WovF only) ----------------
__global__ __launch_bounds__(256) void sgemm_k(const float* __restrict__ A, const float* __restrict__ B,
                                               float* __restrict__ C, int M, int N, int K){
  __shared__ float As[16][128];
  __shared__ float Bs[16][64];
  int tid = threadIdx.x;
  int tx = tid & 15, ty = tid >> 4;
  int rowBase = blockIdx.x * 128;
  int colBase = blockIdx.y * 64;
  float acc[8][4];
  #pragma unroll
  for (int i=0;i<8;i++)
    #pragma unroll
    for (int j=0;j<4;j++) acc[i][j]=0.f;
  for (int k0=0;k0<K;k0+=16){
    #pragma unroll
    for (int ss=0; ss<2; ss++){
      int s = tid + ss*256;
      int r = s >> 2;
      int kk = (s & 3)*4;
      float4 v = make_float4(0.f,0.f,0.f,0.f);
      int grow = rowBase + r;
      if (grow < M) v = *(const float4*)(A + (size_t)grow*K + k0 + kk);
      As[kk+0][r]=v.x; As[kk+1][r]=v.y; As[kk+2][r]=v.z; As[kk+3][r]=v.w;
    }
    {
      int r = tid >> 4, cc = (tid & 15)*4;
      float4 v = *(const float4*)(B + (size_t)(k0+r)*N + colBase + cc);
      *(float4*)&Bs[r][cc] = v;
    }
    __syncthreads();
    #pragma unroll
    for (int kk=0;kk<16;kk++){
      float a[8], b[4];
      *(float4*)&a[0] = *(const float4*)&As[kk][ty*8];
      *(float4*)&a[4] = *(const float4*)&As[kk][ty*8+4];
      *(float4*)&b[0] = *(const float4*)&Bs[kk][tx*4];
      #pragma unroll
      for (int i=0;i<8;i++)
        #pragma unroll
        for (int j=0;j<4;j++)
          acc[i][j] = fmaf(a[i], b[j], acc[i][j]);
    }
    __syncthreads();
  }
  #pragma unroll
  for (int i=0;i<8;i++){
    int gr = rowBase + ty*8 + i;
    if (gr >= M) continue;
    float4 v = make_float4(acc[i][0], acc[i][1], acc[i][2], acc[i][3]);
    *(float4*)(C + (size_t)gr*N + colBase + tx*4) = v;
  }
}

// ---------------- bf16 MFMA GEMM, 256 threads (RR-sized GRU GEMMs, N=768) ----------------
// EPI: 0 plain(+bias); 8 v += e1-matrix.
template<int EPI, int HASB>
__global__ __launch_bounds__(256) void mgemm_k(
    const bf16_t* __restrict__ A0, const bf16_t* __restrict__ Bt,
    float* __restrict__ C, const float* __restrict__ bias,
    int M, int N, int K, const float* __restrict__ e1){
  __shared__ bf16_t As[128*64];
  __shared__ bf16_t Bs[128*64];
  int tid = threadIdx.x;
  int lane = tid & 63, w = tid >> 6;
  int wm = w >> 1, wn = w & 1;
  int rowBase = blockIdx.x * 128;
  int colBase = blockIdx.y * 128;
  f32x4 acc[4][4] = {};

  int lrow = lane >> 3;
  int p    = lane & 7;
  int arow[4];
  #pragma unroll
  for (int c = 0; c < 4; c++){
    int gr = rowBase + c*32 + w*8 + lrow;
    arow[c] = min(gr, M-1);
  }
  for (int k0 = 0; k0 < K; k0 += 64){
    #pragma unroll
    for (int c = 0; c < 4; c++){
      int r = c*32 + w*8 + lrow;
      int s = p ^ (r & 7);
      gload_lds16(A0 + (size_t)arow[c]*K + k0 + s*8, As + (size_t)(c*32 + w*8)*64);
      int gb = colBase + r;
      gload_lds16(Bt + (size_t)gb*K + k0 + s*8, Bs + (size_t)(c*32 + w*8)*64);
    }
    asm volatile("s_waitcnt vmcnt(0)" ::: "memory");
    __syncthreads();
    #pragma unroll
    for (int kk = 0; kk < 2; kk++){
      bf16x8 af[4], bfr[4];
      int sg = kk*4 + (lane >> 4);
      #pragma unroll
      for (int i = 0; i < 4; i++){
        int r = wm*64 + i*16 + (lane & 15);
        af[i] = *(const bf16x8*)(As + r*64 + (sg ^ (r & 7))*8);
      }
      #pragma unroll
      for (int j = 0; j < 4; j++){
        int rn = wn*64 + j*16 + (lane & 15);
        bfr[j] = *(const bf16x8*)(Bs + rn*64 + (sg ^ (rn & 7))*8);
      }
      #pragma unroll
      for (int i = 0; i < 4; i++)
        #pragma unroll
        for (int j = 0; j < 4; j++)
          acc[i][j] = __builtin_amdgcn_mfma_f32_16x16x32_bf16(af[i], bfr[j], acc[i][j], 0, 0, 0);
    }
    __syncthreads();
  }
  int colv[4]; float bb[4];
  #pragma unroll
  for (int j = 0; j < 4; j++){
    colv[j] = colBase + wn*64 + j*16 + (lane & 15);
    bb[j] = HASB ? bias[colv[j]] : 0.f;
  }
  #pragma unroll
  for (int i = 0; i < 4; i++){
    #pragma unroll
    for (int q = 0; q < 4; q++){
      int grt = rowBase + wm*64 + i*16 + ((lane >> 4) << 2) + q;
      if (grt >= M) continue;
      #pragma unroll
      for (int j = 0; j < 4; j++){
        size_t idx = (size_t)grt*N + colv[j];
        float v = acc[i][j][q] + bb[j];
        if (EPI == 8) v += e1[idx];
        C[idx] = v;
      }
    }
  }
}

// ---------------- bf16 MFMA GEMM, 512 threads, BM=128 BN=256 (full-width, A read ONCE) ----------------
// 8 waves (2 wm x 4 wn), each wave 64x64, acc[4][4]. N fixed = 256.
// SPLITA: K=512, k<256 from A0, k>=256 from A1 (both stride 256).
// EPI: 0 plain(+bias)->Cb; 2 tanh(v+pos+bias)->Cb [e1=pos, e2=WP]; 3 gate-blend->C f32:
//      g=sigm(v+bias), C=g*eb+(1-g)*eb2; 4 deg-aware leaky->Cb; 5 deg0 fix (rows via z)->Cb;
//      7 sigm(v+bias)->Cb.
template<int EPI, int WF32, int WBF, int HASB, int SPLITA>
__global__ __launch_bounds__(512) void mgemm2_k(
    const bf16_t* __restrict__ A0, const bf16_t* __restrict__ A1,
    const bf16_t* __restrict__ Bt,
    float* __restrict__ C, bf16_t* __restrict__ Cb, const float* __restrict__ bias,
    int M, int K,
    const float* __restrict__ e1, const float* __restrict__ e2,
    const bf16_t* __restrict__ eb, const bf16_t* __restrict__ eb2,
    const int* __restrict__ degp, const int* __restrict__ z, const int* __restrict__ nzp){
  int rowBase = blockIdx.x * 128;
  int nzv = 0;
  if (EPI == 5){
    nzv = nzp[0];
    if (rowBase >= nzv) return;
  }
  __shared__ bf16_t As[128*64];   // 16 KB
  __shared__ bf16_t Bs[256*64];   // 32 KB
  int tid = threadIdx.x;
  int lane = tid & 63, w = tid >> 6;       // w 0..7
  int wm = w >> 2, wn = w & 3;
  f32x4 acc[4][4] = {};

  int lrow8 = lane >> 3;          // 0..7
  int p     = lane & 7;           // phys 16B seg
  // A staging: wave w covers rows w*16 + c*8 + lrow8, c=0..1
  int arow[2];
  #pragma unroll
  for (int c = 0; c < 2; c++){
    int r = w*16 + c*8 + lrow8;
    int gr = rowBase + r;
    if (EPI == 5) arow[c] = z[min(gr, nzv-1)];
    else          arow[c] = min(gr, M-1);
  }
  for (int k0 = 0; k0 < K; k0 += 64){
    const bf16_t* Ap; int koff; size_t lda;
    if (SPLITA){ Ap = (k0 < 256) ? A0 : A1; koff = k0 & 255; lda = 256; }
    else       { Ap = A0; koff = k0; lda = (size_t)K; }
    #pragma unroll
    for (int c = 0; c < 2; c++){
      int r = w*16 + c*8 + lrow8;
      int s = p ^ (r & 7);                 // both-sides swizzle
      gload_lds16(Ap + (size_t)arow[c]*lda + koff + s*8, As + (size_t)(w*16 + c*8)*64);
    }
    #pragma unroll
    for (int c = 0; c < 4; c++){
      int r = w*32 + c*8 + lrow8;          // 0..255
      int s = p ^ (r & 7);
      gload_lds16(Bt + (size_t)r*K + k0 + s*8, Bs + (size_t)(w*32 + c*8)*64);
    }
    asm volatile("s_waitcnt vmcnt(0)" ::: "memory");
    __syncthreads();
    #pragma unroll
    for (int kk = 0; kk < 2; kk++){
      bf16x8 af[4], bfr[4];
      int sg = kk*4 + (lane >> 4);         // logical seg 0..7
      #pragma unroll
      for (int i = 0; i < 4; i++){
        int r = wm*64 + i*16 + (lane & 15);
        af[i] = *(const bf16x8*)(As + r*64 + (sg ^ (r & 7))*8);
      }
      #pragma unroll
      for (int j = 0; j < 4; j++){
        int rn = wn*64 + j*16 + (lane & 15);
        bfr[j] = *(const bf16x8*)(Bs + rn*64 + (sg ^ (rn & 7))*8);
      }
      #pragma unroll
      for (int i = 0; i < 4; i++)
        #pragma unroll
        for (int j = 0; j < 4; j++)
          acc[i][j] = __builtin_amdgcn_mfma_f32_16x16x32_bf16(af[i], bfr[j], acc[i][j], 0, 0, 0);
    }
    __syncthreads();
  }
  // ---- epilogue (N = 256) ----
  int colv[4]; float bb[4], wp0[4], wp1[4], wp2[4];
  #pragma unroll
  for (int j = 0; j < 4; j++){
    colv[j] = wn*64 + j*16 + (lane & 15);
    bb[j] = HASB ? bias[colv[j]] : 0.f;
    if (EPI == 2){ wp0[j] = e2[colv[j]]; wp1[j] = e2[256+colv[j]]; wp2[j] = e2[512+colv[j]]; }
  }
  #pragma unroll
  for (int i = 0; i < 4; i++){
    #pragma unroll
    for (int q = 0; q < 4; q++){
      int grt = rowBase + wm*64 + i*16 + ((lane >> 4) << 2) + q;
      if (EPI == 5){ if (grt >= nzv) continue; }
      else         { if (grt >= M) continue; }
      int orow = (EPI == 5) ? z[grt] : grt;
      int dflag = 0;
      if (EPI == 4) dflag = degp[orow];
      float p0=0.f, p1=0.f, p2=0.f;
      if (EPI == 2){ p0 = e1[(size_t)grt*3]; p1 = e1[(size_t)grt*3+1]; p2 = e1[(size_t)grt*3+2]; }
      #pragma unroll
      for (int j = 0; j < 4; j++){
        size_t idx = (size_t)orow*256 + colv[j];
        float v = acc[i][j][q] + bb[j];
        if (EPI == 2) v = tanhf(v + p0*wp0[j] + p1*wp1[j] + p2*wp2[j]);
        if (EPI == 3){
          float g = sigm(v);
          v = g*(float)eb[idx] + (1.f-g)*(float)eb2[idx];
        }
        if (EPI == 4) v = (dflag > 0) ? leaky(v) : v;
        if (EPI == 5){
          float praw = (float)Cb[idx];
          v = leaky(praw + v);
        }
        if (EPI == 7) v = sigm(v);
        if (WF32) C[idx] = v;
        if (WBF)  Cb[idx] = (bf16_t)v;
      }
    }
  }
}

// ---------------- row-wise L2 normalize -> bf16 (setup) ----------------
__global__ __launch_bounds__(256) void l2norm_k(const float* __restrict__ in, bf16_t* __restrict__ outb){
  int i = blockIdx.x, c = threadIdx.x;
  size_t idx = (size_t)i*HH + c;
  float v = in[idx];
  float ss = v*v;
  #pragma unroll
  for (int o=32;o;o>>=1) ss += __shfl_down(ss, o);
  __shared__ float red[4];
  if ((threadIdx.x & 63)==0) red[threadIdx.x>>6] = ss;
  __syncthreads();
  float tot = red[0]+red[1]+red[2]+red[3];
  outb[idx] = (bf16_t)(v / fmaxf(sqrtf(tot), 1e-12f));
}

// ---------------- batched combined histogram over all 3 t's ----------------
__global__ __launch_bounds__(256) void hist3_k(const int* __restrict__ r_seg, const int* __restrict__ dst,
                                               int* __restrict__ cnt){
  int q = blockIdx.x*256 + threadIdx.x;
  if (q >= 3*2*EE) return;
  int t = q / (2*EE);
  int e = q - t*2*EE;
  if (e < EE) atomicAdd(cnt + t*NBIN + r_seg[(size_t)t*EE + e], 1);
  else        atomicAdd(cnt + t*NBIN + RR + dst[(size_t)t*EE + (e-EE)], 1);
}

// ---------------- hierarchical exclusive scan ----------------
__global__ __launch_bounds__(1024) void scan1_k(const int* __restrict__ cnt, int* __restrict__ start,
                                                int* __restrict__ bsum, int n){
  __shared__ int s[1024];
  int t = blockIdx.x*1024 + threadIdx.x;
  int v = (t < n) ? cnt[t] : 0;
  s[threadIdx.x] = v;
  __syncthreads();
  for (int off = 1; off < 1024; off <<= 1){
    int x = (threadIdx.x >= off) ? s[threadIdx.x - off] : 0;
    __syncthreads();
    s[threadIdx.x] += x;
    __syncthreads();
  }
  if (t < n) start[t] = s[threadIdx.x] - v;
  if (threadIdx.x == 1023) bsum[blockIdx.x] = s[1023];
}
__global__ __launch_bounds__(256) void scan2_k(const int* __restrict__ bsum, int* __restrict__ boff,
                                               int* __restrict__ start, int nb, int n){
  __shared__ int s[256];
  int t = threadIdx.x;
  int v = (t < nb) ? bsum[t] : 0;
  s[t] = v;
  __syncthreads();
  for (int off = 1; off < 256; off <<= 1){
    int x = (t >= off) ? s[t-off] : 0;
    __syncthreads();
    s[t] += x;
    __syncthreads();
  }
  if (t < nb) boff[t] = s[t] - v;
  if (t == 255) start[n] = s[255];
}
__global__ __launch_bounds__(1024) void scan3_k(int* __restrict__ start, int* __restrict__ cur,
                                                const int* __restrict__ boff, int n){
  int t = blockIdx.x*1024 + threadIdx.x;
  if (t < n){
    int v = start[t] + boff[blockIdx.x];
    start[t] = v;
    cur[t] = v;
  }
}

// ---------------- batched CSR fill (dst side packs src|ety<<16 into u32) ----------------
__global__ __launch_bounds__(256) void fill3_k(const int* __restrict__ r_seg, const int* __restrict__ r_to_e,
    const int* __restrict__ dst, const int* __restrict__ src, const int* __restrict__ ety,
    int* __restrict__ cur, int* __restrict__ rnode, unsigned* __restrict__ dpack){
  int q = blockIdx.x*256 + threadIdx.x;
  if (q >= 3*2*EE) return;
  int t = q / (2*EE);
  int e = q - t*2*EE;
  if (e < EE){
    size_t ge = (size_t)t*EE + e;
    int pp = atomicAdd(cur + t*NBIN + r_seg[ge], 1);
    rnode[pp - EE*t] = r_to_e[ge];
  } else {
    size_t ge = (size_t)t*EE + (e - EE);
    int pp = atomicAdd(cur + t*NBIN + RR + dst[ge], 1);
    dpack[pp - EE*(t+1)] = (unsigned)src[ge] | ((unsigned)ety[ge] << 16);
  }
}

// ---------------- batched compact deg-0 node lists (wave-aggregated atomics) ----------------
__global__ __launch_bounds__(256) void compact3_k(const int* __restrict__ cnt, int* __restrict__ zAll,
                                                  int* __restrict__ nz){
  int q = blockIdx.x*256 + threadIdx.x;
  int lane = threadIdx.x & 63;
  bool valid = q < 3*NN;
  int qc = valid ? q : 3*NN - 1;
  int t = qc / NN, d = qc - t*NN;
  bool pred = valid && (cnt[t*NBIN + RR + d] == 0);
  int tA = __shfl(t, 0), tB = __shfl(t, 63);
  if (tA == tB){
    unsigned long long m = __ballot(pred);
    int total = __popcll(m);
    int base = 0;
    if (lane == 0 && total > 0) base = atomicAdd(nz + tA, total);
    base = __shfl(base, 0);
    if (pred){
      int myoff = __popcll(m & ((1ULL << lane) - 1ULL));
      zAll[(size_t)tA*NN + base + myoff] = d;
    }
  } else {
    if (pred){
      int pp = atomicAdd(nz + t, 1);
      zAll[(size_t)t*NN + pp] = d;
    }
  }
}

// per-relation mean of h rows (bf16 out)
__global__ __launch_bounds__(256) void rmean_k(const int* __restrict__ startT, const int* __restrict__ rnode,
    const bf16_t* __restrict__ hb, bf16_t* __restrict__ meanb, int rbase){
  int r = blockIdx.x, c = threadIdx.x;
  int s0 = startT[r] - rbase, s1 = startT[r+1] - rbase;
  float acc = 0.f, acc2 = 0.f;
  int i = s0;
  for (; i + 1 < s1; i += 2){
    acc  += (float)hb[(size_t)rnode[i]*HH + c];
    acc2 += (float)hb[(size_t)rnode[i+1]*HH + c];
  }
  if (i < s1) acc += (float)hb[(size_t)rnode[i]*HH + c];
  acc += acc2;
  int cnt = s1 - s0;
  meanb[(size_t)r*HH + c] = (bf16_t)((cnt > 0) ? acc/(float)cnt : 0.f);
}

// ---------------- GRU gates + row l2norm, in-place h0 (f32) + bf16 shadow ----------------
__global__ __launch_bounds__(256) void gru_gate_k(const float* __restrict__ gi,
    const float* __restrict__ ghb, float* __restrict__ h0, bf16_t* __restrict__ h0b){
  int r = blockIdx.x, c = threadIdx.x;
  float ir = gi[(size_t)r*768 + c],       hr = ghb[(size_t)r*768 + c];
  float iz = gi[(size_t)r*768 + 256 + c], hz = ghb[(size_t)r*768 + 256 + c];
  float in_ = gi[(size_t)r*768 + 512 + c], hn = ghb[(size_t)r*768 + 512 + c];
  float rg = sigm(ir + hr);
  float z  = sigm(iz + hz);
  float n  = tanhf(in_ + rg*hn);
  float hp = h0[(size_t)r*HH + c];
  float v = (1.f - z)*n + z*hp;
  float ss = v*v;
  #pragma unroll
  for (int o=32;o;o>>=1) ss += __shfl_down(ss, o);
  __shared__ float red[4];
  if ((threadIdx.x & 63)==0) red[threadIdx.x>>6] = ss;
  __syncthreads();
  float tot = red[0]+red[1]+red[2]+red[3];
  float nv = v / fmaxf(sqrtf(tot), 1e-12f);
  h0[(size_t)r*HH + c] = nv;
  h0b[(size_t)r*HH + c] = (bf16_t)nv;
}

// ---------------- gather mean messages (packed u32 edge payload) ----------------
__global__ __launch_bounds__(256) void gatherM_k(const bf16_t* __restrict__ nin,
    const bf16_t* __restrict__ h0b, const int* __restrict__ startT,
    const unsigned* __restrict__ dpack, bf16_t* __restrict__ Amean, int ebase){
  int w = threadIdx.x >> 6, ln = threadIdx.x & 63;
  int d = blockIdx.x*4 + w;
  if (d >= NN) return;
  int s0 = startT[RR + d] - ebase, s1 = startT[RR + d + 1] - ebase;
  int deg = s1 - s0;
  float a0=0.f, a1=0.f, a2=0.f, a3=0.f;
  for (int i = s0; i < s1; i++){
    unsigned se = dpack[i];
    int s = (int)(se & 0xffffu);
    int r = (int)(se >> 16);
    uint2 ra = *(const uint2*)(nin + (size_t)s*HH + ln*4);
    uint2 rb = *(const uint2*)(h0b + (size_t)r*HH + ln*4);
    a0 += __uint_as_float((ra.x & 0xffffu) << 16) + __uint_as_float((rb.x & 0xffffu) << 16);
    a1 += __uint_as_float(ra.x & 0xffff0000u)     + __uint_as_float(rb.x & 0xffff0000u);
    a2 += __uint_as_float((ra.y & 0xffffu) << 16) + __uint_as_float((rb.y & 0xffffu) << 16);
    a3 += __uint_as_float(ra.y & 0xffff0000u)     + __uint_as_float(rb.y & 0xffff0000u);
  }
  float inv = (deg > 0) ? 1.f/(float)deg : 0.f;
  bf16_t m[4] = { (bf16_t)(a0*inv), (bf16_t)(a1*inv), (bf16_t)(a2*inv), (bf16_t)(a3*inv) };
  *(uint2*)(Amean + (size_t)d*HH + ln*4) = *(const uint2*)m;
}

// ---------------- fused l2norm(nh2_bf) + time-gate h update (bf16 state, in-place, same-thread) ----------------
__global__ __launch_bounds__(256) void l2up_k(const bf16_t* __restrict__ nh2b, const bf16_t* __restrict__ sg,
    bf16_t* __restrict__ hb){
  int i = blockIdx.x, c = threadIdx.x;
  size_t idx = (size_t)i*HH + c;
  float v = (float)nh2b[idx];
  float ss = v*v;
  #pragma unroll
  for (int o=32;o;o>>=1) ss += __shfl_down(ss, o);
  __shared__ float red[4];
  if ((threadIdx.x & 63)==0) red[threadIdx.x>>6] = ss;
  __syncthreads();
  float tot = red[0]+red[1]+red[2]+red[3];
  float curn = v / fmaxf(sqrtf(tot), 1e-12f);
  float s = (float)sg[idx];
  float hn = s*curn + (1.f-s)*(float)hb[idx];
  hb[idx] = (bf16_t)hn;
}

extern "C" void kernel_launch(void* const* d_in, const int* in_sizes, int n_in,
                              void* d_out, int out_size, void* d_ws, size_t ws_size,
                              hipStream_t stream) {
  const int*   src     = (const int*)  d_in[0];
  const int*   dst     = (const int*)  d_in[1];
  const int*   etype   = (const int*)  d_in[2];
  const int*   r_to_e  = (const int*)  d_in[3];
  const int*   r_seg   = (const int*)  d_in[4];
  const float* pos_enc = (const float*)d_in[5];
  const float* dyn_emb = (const float*)d_in[6];
  const float* emb_rel = (const float*)d_in[7];
  const float* gW_ih   = (const float*)d_in[8];
  const float* gW_hh   = (const float*)d_in[9];
  const float* gb_ih   = (const float*)d_in[10];
  const float* gb_hh   = (const float*)d_in[11];
  const float* W_neigh = (const float*)d_in[12];
  const float* W_loop  = (const float*)d_in[13];
  const float* W_evolve= (const float*)d_in[14];
  const float* W_hp    = (const float*)d_in[15];
  const float* b_hp    = (const float*)d_in[16];
  const float* W_v     = (const float*)d_in[17];
  const float* b_v     = (const float*)d_in[18];
  const float* W_o     = (const float*)d_in[19];
  const float* b_o     = (const float*)d_in[20];
  const float* time_W  = (const float*)d_in[21];
  const float* time_b  = (const float*)d_in[22];
  const float* glob_W  = (const float*)d_in[23];
  const float* glob_b  = (const float*)d_in[24];
  float* out = (float*)d_out;
  (void)in_sizes; (void)n_in; (void)out_size; (void)ws_size;

  char* ws = (char*)d_ws;
  size_t off = 0;
  auto allocB = [&](size_t bytes)->char*{
    char* pp = ws + off; off += (bytes + 255) & ~(size_t)255;
    return pp;
  };
  float*  tmp    = (float*) allocB(NHf*4);          // Amean (bf16, 1st half) + sgate (bf16, 2nd half)
  bf16_t* h_bf   = (bf16_t*)allocB(NHf*2);          // recurrent state (bf16)
  bf16_t* nh_bf  = (bf16_t*)allocB(NHf*2);          // layer-0 out; aliased: attn_bf
  bf16_t* nh2_bf = (bf16_t*)allocB(NHf*2);
  bf16_t* gh_bf  = (bf16_t*)allocB(NHf*2);
  bf16_t* Amean  = (bf16_t*)tmp;
  bf16_t* sgate  = (bf16_t*)(tmp + NHf/2);
  bf16_t* attn_bf= nh_bf;

  float*  h0    = (float*) allocB((size_t)RR*HH*4);
  bf16_t* h0b   = (bf16_t*)allocB((size_t)RR*HH*2);
  bf16_t* meanb = (bf16_t*)allocB((size_t)RR*HH*2);
  float*  gi0   = (float*) allocB((size_t)RR*768*4);
  float*  gi    = (float*) allocB((size_t)RR*768*4);
  float*  ghb   = (float*) allocB((size_t)RR*768*4);
  bf16_t* wihAT = (bf16_t*)allocB((size_t)768*256*2);
  bf16_t* wihBT = (bf16_t*)allocB((size_t)768*256*2);
  bf16_t* whhT  = (bf16_t*)allocB((size_t)768*256*2);
  float*  WP    = (float*) allocB((size_t)PP*HH*4);
  float*  WovF  = (float*) allocB((size_t)HH*HH*4);
  float*  b_ov  = (float*) allocB((size_t)HH*4);
  bf16_t* bst2  = (bf16_t*)allocB((size_t)2*HH*512*2);   // per-layer [Wn|Wl]^T, ld 512
  bf16_t* wdT   = (bf16_t*)allocB((size_t)2*HH*HH*2);    // per-layer (We-Wl)^T
  bf16_t* whpT  = (bf16_t*)allocB((size_t)HH*HH*2);
  bf16_t* wovT  = (bf16_t*)allocB((size_t)HH*HH*2);
  bf16_t* timT  = (bf16_t*)allocB((size_t)HH*HH*2);
  bf16_t* globT = (bf16_t*)allocB((size_t)HH*HH*2);
  int* cnt    = (int*)allocB((size_t)(NBIN3+4)*4);       // + nz[3] at tail
  int* start  = (int*)allocB((size_t)(NBIN3+1)*4);
  int* cur    = (int*)allocB((size_t)NBIN3*4);
  int* rnode  = (int*)allocB((size_t)3*EE*4);
  unsigned* dpack = (unsigned*)allocB((size_t)3*EE*4);
  int* zAll   = (int*)allocB((size_t)3*NN*4);
  int* bsum   = (int*)allocB(256*4);
  int* boff   = (int*)allocB(256*4);
  int* nz     = cnt + NBIN3;

  const int MT  = (NN + 127)/128;            // 391 row tiles
  const int NB3 = (NBIN3 + 1023)/1024;       // 148 scan blocks

  // ---- setup: weight prep + initial h/h0 + gi0 ----
  copyall_k<<<dim3(768,5), 256, 0, stream>>>(gW_ih, gW_hh, W_hp, emb_rel,
                                             wihAT, wihBT, whhT, whpT, h0b);
  tconv_all_k<<<dim3(8,8,8), 256, 0, stream>>>(W_neigh, W_loop, W_evolve, time_W, glob_W,
                                               bst2, wdT, timT, globT);
  misc_k<<<2, 256, 0, stream>>>(W_hp, WP, W_o, b_v, b_o, b_ov);
  sgemm_k<<<dim3(2,4), 256, 0, stream>>>(W_o, W_v, WovF, 256, 256, 256);
  copy_bfw_k<<<HH, 256, 0, stream>>>(WovF, wovT);
  l2norm_k<<<NN, 256, 0, stream>>>(dyn_emb, h_bf);
  hipMemcpyAsync(h0, emb_rel, (size_t)RR*HH*4, hipMemcpyDeviceToDevice, stream);
  // gi0 = emb_rel @ W_ih[:, :256]^T + b_ih   (h0b == emb_rel bf16 at this point)
  mgemm_k<0,1><<<dim3(4,6), 256, 0, stream>>>(h0b, wihAT, gi0, gb_ih, RR, 768, 256, nullptr);

  // ---- batched CSR build for all 3 snapshots ----
  hipMemsetAsync(cnt, 0, (size_t)(NBIN3+4)*4, stream);
  hist3_k<<<(6*EE+255)/256, 256, 0, stream>>>(r_seg, dst, cnt);
  scan1_k<<<NB3, 1024, 0, stream>>>(cnt, start, bsum, NBIN3);
  scan2_k<<<1, 256, 0, stream>>>(bsum, boff, start, NB3, NBIN3);
  scan3_k<<<NB3, 1024, 0, stream>>>(start, cur, boff, NBIN3);
  fill3_k<<<(6*EE+255)/256, 256, 0, stream>>>(r_seg, r_to_e, dst, src, etype, cur, rnode, dpack);
  compact3_k<<<(3*NN+255)/256, 256, 0, stream>>>(cnt, zAll, nz);

  for (int t=0; t<TT; t++){
    const float* posT = pos_enc + (size_t)t*NN*PP;
    const int* startT = start + (size_t)t*NBIN;
    const int* degT   = cnt + (size_t)t*NBIN + RR;
    const int* zT     = zAll + (size_t)t*NN;
    const int* nzT    = nz + t;

    // ---- relation mean + GRU ----
    rmean_k<<<RR, 256, 0, stream>>>(startT, rnode, h_bf, meanb, EE*t);
    mgemm_k<8,0><<<dim3(4,6), 256, 0, stream>>>(meanb, wihBT, gi, nullptr, RR, 768, 256, gi0);
    mgemm_k<0,1><<<dim3(4,6), 256, 0, stream>>>(h0b, whhT, ghb, gb_hh, RR, 768, 256, nullptr);
    gru_gate_k<<<RR, 256, 0, stream>>>(gi, ghb, h0, h0b);

    // ---- RGCN layer 0 ----
    gatherM_k<<<(NN+3)/4, 256, 0, stream>>>(h_bf, h0b, startT, dpack, Amean, EE*(t+1));
    mgemm2_k<4,0,1,0,1><<<MT, 512, 0, stream>>>(Amean, h_bf, bst2, nullptr, nh_bf, nullptr,
        NN, 512, nullptr, nullptr, nullptr, nullptr, degT, nullptr, nullptr);
    mgemm2_k<5,0,1,0,0><<<MT, 512, 0, stream>>>(h_bf, nullptr, wdT, nullptr, nh_bf, nullptr,
        NN, 256, nullptr, nullptr, nullptr, nullptr, nullptr, zT, nzT);

    // ---- RGCN layer 1 ----
    gatherM_k<<<(NN+3)/4, 256, 0, stream>>>(nh_bf, h0b, startT, dpack, Amean, EE*(t+1));
    mgemm2_k<4,0,1,0,1><<<MT, 512, 0, stream>>>(Amean, nh_bf, bst2 + (size_t)HH*512, nullptr, nh2_bf, nullptr,
        NN, 512, nullptr, nullptr, nullptr, nullptr, degT, nullptr, nullptr);
    mgemm2_k<5,0,1,0,0><<<MT, 512, 0, stream>>>(nh_bf, nullptr, wdT + (size_t)HH*HH, nullptr, nh2_bf, nullptr,
        NN, 256, nullptr, nullptr, nullptr, nullptr, nullptr, zT, nzT);

    // ---- attention chain ----
    mgemm2_k<2,0,1,1,0><<<MT, 512, 0, stream>>>(nh2_bf, nullptr, whpT, nullptr, attn_bf, b_hp,
        NN, 256, posT, WP, nullptr, nullptr, nullptr, nullptr, nullptr);
    mgemm2_k<0,0,1,1,0><<<MT, 512, 0, stream>>>(attn_bf, nullptr, wovT, nullptr, gh_bf, b_ov,
        NN, 256, nullptr, nullptr, nullptr, nullptr, nullptr, nullptr, nullptr);

    // ---- time gate (sigmoid in epilogue, bf16), fused norm+update (in-place bf16 h), glob+blend ----
    mgemm2_k<7,0,1,1,0><<<MT, 512, 0, stream>>>(h_bf, nullptr, timT, nullptr, sgate, time_b,
        NN, 256, nullptr, nullptr, nullptr, nullptr, nullptr, nullptr, nullptr);
    l2up_k<<<NN, 256, 0, stream>>>(nh2_bf, sgate, h_bf);
    mgemm2_k<3,1,0,1,0><<<MT, 512, 0, stream>>>(h_bf, nullptr, globT, out + (size_t)t*NHf, nullptr, glob_b,
        NN, 256, nullptr, nullptr, gh_bf, h_bf, nullptr, nullptr, nullptr);
  }
}

// Round 13
// 1329.393 us; speedup vs baseline: 1.2351x; 1.0306x over previous
//
#include <hip/hip_runtime.h>
#include <math.h>

#define NN 50000
#define HH 256
#define RR 460
#define TT 3
#define EE 100000
#define PP 3
#define SLOPE 0.22916666666666666f
#define NBIN (RR + NN)           // per-t bins: 50460
#define NBIN3 (3*NBIN)           // batched bins

typedef __bf16 bf16_t;
typedef bf16_t bf16x8 __attribute__((ext_vector_type(8)));
typedef float f32x4 __attribute__((ext_vector_type(4)));

static const size_t NHf = (size_t)NN * HH;   // 12.8M elements

__device__ __forceinline__ float sigm(float x){ return 1.0f/(1.0f+__expf(-x)); }
__device__ __forceinline__ float leaky(float x){ return (x >= 0.f) ? x : SLOPE*x; }

__device__ __forceinline__ void gload_lds16(const void* g, void* l){
  __builtin_amdgcn_global_load_lds((const __attribute__((address_space(1))) void*)g,
                                   (__attribute__((address_space(3))) void*)l, 16, 0, 0);
}

// ---------------- merged weight transposes (sub fused for Wd): 8 jobs via blockIdx.z ----------------
__global__ __launch_bounds__(256) void tconv_all_k(
    const float* __restrict__ Wn, const float* __restrict__ Wl, const float* __restrict__ We,
    const float* __restrict__ timW, const float* __restrict__ globW,
    bf16_t* __restrict__ bst2, bf16_t* __restrict__ wdT,
    bf16_t* __restrict__ timT, bf16_t* __restrict__ globT){
  int z = blockIdx.z;
  const float* in; const float* in2 = nullptr; bf16_t* outp; int ldout;
  switch(z){
    case 0: in = Wn;           outp = bst2;                       ldout = 512; break;
    case 1: in = Wl;           outp = bst2 + 256;                 ldout = 512; break;
    case 2: in = Wn + 65536;   outp = bst2 + (size_t)256*512;     ldout = 512; break;
    case 3: in = Wl + 65536;   outp = bst2 + (size_t)256*512+256; ldout = 512; break;
    case 4: in = We;          in2 = Wl;         outp = wdT;         ldout = 256; break;
    case 5: in = We + 65536;  in2 = Wl + 65536; outp = wdT + 65536; ldout = 256; break;
    case 6: in = timW;  outp = timT;  ldout = 256; break;
    default:in = globW; outp = globT; ldout = 256; break;
  }
  __shared__ float tile[32][33];
  int n0 = blockIdx.x*32, k0 = blockIdx.y*32;
  int tx = threadIdx.x & 31, ty = threadIdx.x >> 5;
  #pragma unroll
  for (int j=0;j<4;j++){
    size_t idx = (size_t)(k0+ty+j*8)*256 + n0+tx;
    float v = in[idx];
    if (in2) v -= in2[idx];
    tile[ty+j*8][tx] = v;
  }
  __syncthreads();
  #pragma unroll
  for (int j=0;j<4;j++)
    outp[(size_t)(n0+ty+j*8)*ldout + k0+tx] = (bf16_t)tile[tx][ty+j*8];
}

// ---------------- merged row copy+convert jobs via blockIdx.y ----------------
__global__ __launch_bounds__(256) void copyall_k(const float* __restrict__ gW_ih,
    const float* __restrict__ gW_hh, const float* __restrict__ W_hp, const float* __restrict__ emb_rel,
    bf16_t* __restrict__ wihAT, bf16_t* __restrict__ wihBT, bf16_t* __restrict__ whhT,
    bf16_t* __restrict__ whpT, bf16_t* __restrict__ h0b){
  int r = blockIdx.x, c = threadIdx.x, y = blockIdx.y;
  if (y == 0)      wihAT[(size_t)r*256+c] = (bf16_t)gW_ih[(size_t)r*512 + c];
  else if (y == 1) wihBT[(size_t)r*256+c] = (bf16_t)gW_ih[(size_t)r*512 + 256 + c];
  else if (y == 2) whhT[(size_t)r*256+c]  = (bf16_t)gW_hh[(size_t)r*256 + c];
  else if (y == 3){ if (r < 256) whpT[(size_t)r*256+c] = (bf16_t)W_hp[(size_t)r*259 + c]; }
  else            { if (r < RR)  h0b[(size_t)r*256+c]  = (bf16_t)emb_rel[(size_t)r*256 + c]; }
}

// ---------------- misc small setup: WP extract + b_ov ----------------
__global__ __launch_bounds__(256) void misc_k(const float* __restrict__ W_hp, float* __restrict__ WP,
    const float* __restrict__ W_o, const float* __restrict__ b_v, const float* __restrict__ b_o,
    float* __restrict__ b_ov){
  if (blockIdx.x == 0){
    int j = threadIdx.x;
    #pragma unroll
    for (int p=0;p<PP;p++) WP[p*HH + j] = W_hp[(size_t)j*259 + HH + p];
  } else {
    int n = threadIdx.x;
    float s = b_o[n];
    for (int j=0;j<256;j++) s += W_o[(size_t)n*256+j]*b_v[j];
    b_ov[n] = s;
  }
}

// ---------------- row copy+convert (wovT after sgemm) ----------------
__global__ __launch_bounds__(256) void copy_bfw_k(const float* __restrict__ in, bf16_t* __restrict__ outp){
  int r = blockIdx.x, c = threadIdx.x;
  outp[(size_t)r*HH + c] = (bf16_t)in[(size_t)r*HH + c];
}

// ---------------- f32 SGEMM (setup: WovF only) ----------------
__global__ __launch_bounds__(256) void sgemm_k(const float* __restrict__ A, const float* __restrict__ B,
                                               float* __restrict__ C, int M, int N, int K){
  __shared__ float As[16][128];
  __shared__ float Bs[16][64];
  int tid = threadIdx.x;
  int tx = tid & 15, ty = tid >> 4;
  int rowBase = blockIdx.x * 128;
  int colBase = blockIdx.y * 64;
  float acc[8][4];
  #pragma unroll
  for (int i=0;i<8;i++)
    #pragma unroll
    for (int j=0;j<4;j++) acc[i][j]=0.f;
  for (int k0=0;k0<K;k0+=16){
    #pragma unroll
    for (int ss=0; ss<2; ss++){
      int s = tid + ss*256;
      int r = s >> 2;
      int kk = (s & 3)*4;
      float4 v = make_float4(0.f,0.f,0.f,0.f);
      int grow = rowBase + r;
      if (grow < M) v = *(const float4*)(A + (size_t)grow*K + k0 + kk);
      As[kk+0][r]=v.x; As[kk+1][r]=v.y; As[kk+2][r]=v.z; As[kk+3][r]=v.w;
    }
    {
      int r = tid >> 4, cc = (tid & 15)*4;
      float4 v = *(const float4*)(B + (size_t)(k0+r)*N + colBase + cc);
      *(float4*)&Bs[r][cc] = v;
    }
    __syncthreads();
    #pragma unroll
    for (int kk=0;kk<16;kk++){
      float a[8], b[4];
      *(float4*)&a[0] = *(const float4*)&As[kk][ty*8];
      *(float4*)&a[4] = *(const float4*)&As[kk][ty*8+4];
      *(float4*)&b[0] = *(const float4*)&Bs[kk][tx*4];
      #pragma unroll
      for (int i=0;i<8;i++)
        #pragma unroll
        for (int j=0;j<4;j++)
          acc[i][j] = fmaf(a[i], b[j], acc[i][j]);
    }
    __syncthreads();
  }
  #pragma unroll
  for (int i=0;i<8;i++){
    int gr = rowBase + ty*8 + i;
    if (gr >= M) continue;
    float4 v = make_float4(acc[i][0], acc[i][1], acc[i][2], acc[i][3]);
    *(float4*)(C + (size_t)gr*N + colBase + tx*4) = v;
  }
}

// ---------------- bf16 MFMA GEMM, 256 threads (RR-sized GRU GEMMs, N=768) ----------------
// EPI: 0 plain(+bias); 8 v += e1-matrix.
template<int EPI, int HASB>
__global__ __launch_bounds__(256) void mgemm_k(
    const bf16_t* __restrict__ A0, const bf16_t* __restrict__ Bt,
    float* __restrict__ C, const float* __restrict__ bias,
    int M, int N, int K, const float* __restrict__ e1){
  __shared__ bf16_t As[128*64];
  __shared__ bf16_t Bs[128*64];
  int tid = threadIdx.x;
  int lane = tid & 63, w = tid >> 6;
  int wm = w >> 1, wn = w & 1;
  int rowBase = blockIdx.x * 128;
  int colBase = blockIdx.y * 128;
  f32x4 acc[4][4] = {};

  int lrow = lane >> 3;
  int p    = lane & 7;
  int arow[4];
  #pragma unroll
  for (int c = 0; c < 4; c++){
    int gr = rowBase + c*32 + w*8 + lrow;
    arow[c] = min(gr, M-1);
  }
  for (int k0 = 0; k0 < K; k0 += 64){
    #pragma unroll
    for (int c = 0; c < 4; c++){
      int r = c*32 + w*8 + lrow;
      int s = p ^ (r & 7);
      gload_lds16(A0 + (size_t)arow[c]*K + k0 + s*8, As + (size_t)(c*32 + w*8)*64);
      int gb = colBase + r;
      gload_lds16(Bt + (size_t)gb*K + k0 + s*8, Bs + (size_t)(c*32 + w*8)*64);
    }
    asm volatile("s_waitcnt vmcnt(0)" ::: "memory");
    __syncthreads();
    #pragma unroll
    for (int kk = 0; kk < 2; kk++){
      bf16x8 af[4], bfr[4];
      int sg = kk*4 + (lane >> 4);
      #pragma unroll
      for (int i = 0; i < 4; i++){
        int r = wm*64 + i*16 + (lane & 15);
        af[i] = *(const bf16x8*)(As + r*64 + (sg ^ (r & 7))*8);
      }
      #pragma unroll
      for (int j = 0; j < 4; j++){
        int rn = wn*64 + j*16 + (lane & 15);
        bfr[j] = *(const bf16x8*)(Bs + rn*64 + (sg ^ (rn & 7))*8);
      }
      #pragma unroll
      for (int i = 0; i < 4; i++)
        #pragma unroll
        for (int j = 0; j < 4; j++)
          acc[i][j] = __builtin_amdgcn_mfma_f32_16x16x32_bf16(af[i], bfr[j], acc[i][j], 0, 0, 0);
    }
    __syncthreads();
  }
  int colv[4]; float bb[4];
  #pragma unroll
  for (int j = 0; j < 4; j++){
    colv[j] = colBase + wn*64 + j*16 + (lane & 15);
    bb[j] = HASB ? bias[colv[j]] : 0.f;
  }
  #pragma unroll
  for (int i = 0; i < 4; i++){
    #pragma unroll
    for (int q = 0; q < 4; q++){
      int grt = rowBase + wm*64 + i*16 + ((lane >> 4) << 2) + q;
      if (grt >= M) continue;
      #pragma unroll
      for (int j = 0; j < 4; j++){
        size_t idx = (size_t)grt*N + colv[j];
        float v = acc[i][j][q] + bb[j];
        if (EPI == 8) v += e1[idx];
        C[idx] = v;
      }
    }
  }
}

// ---------------- bf16 MFMA GEMM, 512 threads, BM=64 BN=256 (A read once, high occupancy) ----------------
// 8 waves, wave w owns cols w*32..w*32+31 of all 64 rows; acc[4][2].
// SPLITA: K=512, k<256 from A0, k>=256 from A1 (both stride 256).
// EPI: 0 plain(+bias)->Cb; 2 tanh(v+pos+bias)->Cb [e1=pos, e2=WP]; 3 gate-blend->C f32:
//      g=sigm(v+bias), C=g*eb+(1-g)*eb2; 4 deg-aware leaky->Cb; 5 deg0 fix (rows via z)->Cb;
//      7 sigm(v+bias)->Cb.
template<int EPI, int WF32, int WBF, int HASB, int SPLITA>
__global__ __launch_bounds__(512, 6) void mgemm2_k(
    const bf16_t* __restrict__ A0, const bf16_t* __restrict__ A1,
    const bf16_t* __restrict__ Bt,
    float* __restrict__ C, bf16_t* __restrict__ Cb, const float* __restrict__ bias,
    int M, int K,
    const float* __restrict__ e1, const float* __restrict__ e2,
    const bf16_t* __restrict__ eb, const bf16_t* __restrict__ eb2,
    const int* __restrict__ degp, const int* __restrict__ z, const int* __restrict__ nzp){
  int rowBase = blockIdx.x * 64;
  int nzv = 0;
  if (EPI == 5){
    nzv = nzp[0];
    if (rowBase >= nzv) return;
  }
  __shared__ bf16_t As[64*64];    // 8 KB
  __shared__ bf16_t Bs[256*64];   // 32 KB
  int tid = threadIdx.x;
  int lane = tid & 63, w = tid >> 6;       // w 0..7 = wn
  f32x4 acc[4][2] = {};

  int lrow8 = lane >> 3;          // 0..7
  int p     = lane & 7;           // phys 16B seg
  // A staging: wave w covers rows w*8 + lrow8 (one row-chunk per lane)
  int arow;
  {
    int r = w*8 + lrow8;
    int gr = rowBase + r;
    if (EPI == 5) arow = z[min(gr, nzv-1)];
    else          arow = min(gr, M-1);
  }
  for (int k0 = 0; k0 < K; k0 += 64){
    const bf16_t* Ap; int koff; size_t lda;
    if (SPLITA){ Ap = (k0 < 256) ? A0 : A1; koff = k0 & 255; lda = 256; }
    else       { Ap = A0; koff = k0; lda = (size_t)K; }
    {
      int r = w*8 + lrow8;
      int s = p ^ (r & 7);                 // both-sides swizzle
      gload_lds16(Ap + (size_t)arow*lda + koff + s*8, As + (size_t)(w*8)*64);
    }
    #pragma unroll
    for (int c = 0; c < 4; c++){
      int r = w*32 + c*8 + lrow8;          // 0..255
      int s = p ^ (r & 7);
      gload_lds16(Bt + (size_t)r*K + k0 + s*8, Bs + (size_t)(w*32 + c*8)*64);
    }
    asm volatile("s_waitcnt vmcnt(0)" ::: "memory");
    __syncthreads();
    #pragma unroll
    for (int kk = 0; kk < 2; kk++){
      bf16x8 af[4], bfr[2];
      int sg = kk*4 + (lane >> 4);         // logical seg 0..7
      #pragma unroll
      for (int i = 0; i < 4; i++){
        int r = i*16 + (lane & 15);
        af[i] = *(const bf16x8*)(As + r*64 + (sg ^ (r & 7))*8);
      }
      #pragma unroll
      for (int j = 0; j < 2; j++){
        int rn = w*32 + j*16 + (lane & 15);
        bfr[j] = *(const bf16x8*)(Bs + rn*64 + (sg ^ (rn & 7))*8);
      }
      #pragma unroll
      for (int i = 0; i < 4; i++)
        #pragma unroll
        for (int j = 0; j < 2; j++)
          acc[i][j] = __builtin_amdgcn_mfma_f32_16x16x32_bf16(af[i], bfr[j], acc[i][j], 0, 0, 0);
    }
    __syncthreads();
  }
  // ---- epilogue (N = 256) ----
  int colv[2]; float bb[2], wp0[2], wp1[2], wp2[2];
  #pragma unroll
  for (int j = 0; j < 2; j++){
    colv[j] = w*32 + j*16 + (lane & 15);
    bb[j] = HASB ? bias[colv[j]] : 0.f;
    if (EPI == 2){ wp0[j] = e2[colv[j]]; wp1[j] = e2[256+colv[j]]; wp2[j] = e2[512+colv[j]]; }
  }
  #pragma unroll
  for (int i = 0; i < 4; i++){
    #pragma unroll
    for (int q = 0; q < 4; q++){
      int grt = rowBase + i*16 + ((lane >> 4) << 2) + q;
      if (EPI == 5){ if (grt >= nzv) continue; }
      else         { if (grt >= M) continue; }
      int orow = (EPI == 5) ? z[grt] : grt;
      int dflag = 0;
      if (EPI == 4) dflag = degp[orow];
      float p0=0.f, p1=0.f, p2=0.f;
      if (EPI == 2){ p0 = e1[(size_t)grt*3]; p1 = e1[(size_t)grt*3+1]; p2 = e1[(size_t)grt*3+2]; }
      #pragma unroll
      for (int j = 0; j < 2; j++){
        size_t idx = (size_t)orow*256 + colv[j];
        float v = acc[i][j][q] + bb[j];
        if (EPI == 2) v = tanhf(v + p0*wp0[j] + p1*wp1[j] + p2*wp2[j]);
        if (EPI == 3){
          float g = sigm(v);
          v = g*(float)eb[idx] + (1.f-g)*(float)eb2[idx];
        }
        if (EPI == 4) v = (dflag > 0) ? leaky(v) : v;
        if (EPI == 5){
          float praw = (float)Cb[idx];
          v = leaky(praw + v);
        }
        if (EPI == 7) v = sigm(v);
        if (WF32) C[idx] = v;
        if (WBF)  Cb[idx] = (bf16_t)v;
      }
    }
  }
}

// ---------------- row-wise L2 normalize -> bf16 (setup) ----------------
__global__ __launch_bounds__(256) void l2norm_k(const float* __restrict__ in, bf16_t* __restrict__ outb){
  int i = blockIdx.x, c = threadIdx.x;
  size_t idx = (size_t)i*HH + c;
  float v = in[idx];
  float ss = v*v;
  #pragma unroll
  for (int o=32;o;o>>=1) ss += __shfl_down(ss, o);
  __shared__ float red[4];
  if ((threadIdx.x & 63)==0) red[threadIdx.x>>6] = ss;
  __syncthreads();
  float tot = red[0]+red[1]+red[2]+red[3];
  outb[idx] = (bf16_t)(v / fmaxf(sqrtf(tot), 1e-12f));
}

// ---------------- batched combined histogram over all 3 t's ----------------
__global__ __launch_bounds__(256) void hist3_k(const int* __restrict__ r_seg, const int* __restrict__ dst,
                                               int* __restrict__ cnt){
  int q = blockIdx.x*256 + threadIdx.x;
  if (q >= 3*2*EE) return;
  int t = q / (2*EE);
  int e = q - t*2*EE;
  if (e < EE) atomicAdd(cnt + t*NBIN + r_seg[(size_t)t*EE + e], 1);
  else        atomicAdd(cnt + t*NBIN + RR + dst[(size_t)t*EE + (e-EE)], 1);
}

// ---------------- hierarchical exclusive scan ----------------
__global__ __launch_bounds__(1024) void scan1_k(const int* __restrict__ cnt, int* __restrict__ start,
                                                int* __restrict__ bsum, int n){
  __shared__ int s[1024];
  int t = blockIdx.x*1024 + threadIdx.x;
  int v = (t < n) ? cnt[t] : 0;
  s[threadIdx.x] = v;
  __syncthreads();
  for (int off = 1; off < 1024; off <<= 1){
    int x = (threadIdx.x >= off) ? s[threadIdx.x - off] : 0;
    __syncthreads();
    s[threadIdx.x] += x;
    __syncthreads();
  }
  if (t < n) start[t] = s[threadIdx.x] - v;
  if (threadIdx.x == 1023) bsum[blockIdx.x] = s[1023];
}
__global__ __launch_bounds__(256) void scan2_k(const int* __restrict__ bsum, int* __restrict__ boff,
                                               int* __restrict__ start, int nb, int n){
  __shared__ int s[256];
  int t = threadIdx.x;
  int v = (t < nb) ? bsum[t] : 0;
  s[t] = v;
  __syncthreads();
  for (int off = 1; off < 256; off <<= 1){
    int x = (t >= off) ? s[t-off] : 0;
    __syncthreads();
    s[t] += x;
    __syncthreads();
  }
  if (t < nb) boff[t] = s[t] - v;
  if (t == 255) start[n] = s[255];
}
__global__ __launch_bounds__(1024) void scan3_k(int* __restrict__ start, int* __restrict__ cur,
                                                const int* __restrict__ boff, int n){
  int t = blockIdx.x*1024 + threadIdx.x;
  if (t < n){
    int v = start[t] + boff[blockIdx.x];
    start[t] = v;
    cur[t] = v;
  }
}

// ---------------- batched CSR fill (dst side packs src|ety<<16 into u32) ----------------
__global__ __launch_bounds__(256) void fill3_k(const int* __restrict__ r_seg, const int* __restrict__ r_to_e,
    const int* __restrict__ dst, const int* __restrict__ src, const int* __restrict__ ety,
    int* __restrict__ cur, int* __restrict__ rnode, unsigned* __restrict__ dpack){
  int q = blockIdx.x*256 + threadIdx.x;
  if (q >= 3*2*EE) return;
  int t = q / (2*EE);
  int e = q - t*2*EE;
  if (e < EE){
    size_t ge = (size_t)t*EE + e;
    int pp = atomicAdd(cur + t*NBIN + r_seg[ge], 1);
    rnode[pp - EE*t] = r_to_e[ge];
  } else {
    size_t ge = (size_t)t*EE + (e - EE);
    int pp = atomicAdd(cur + t*NBIN + RR + dst[ge], 1);
    dpack[pp - EE*(t+1)] = (unsigned)src[ge] | ((unsigned)ety[ge] << 16);
  }
}

// ---------------- batched compact deg-0 node lists (wave-aggregated atomics) ----------------
__global__ __launch_bounds__(256) void compact3_k(const int* __restrict__ cnt, int* __restrict__ zAll,
                                                  int* __restrict__ nz){
  int q = blockIdx.x*256 + threadIdx.x;
  int lane = threadIdx.x & 63;
  bool valid = q < 3*NN;
  int qc = valid ? q : 3*NN - 1;
  int t = qc / NN, d = qc - t*NN;
  bool pred = valid && (cnt[t*NBIN + RR + d] == 0);
  int tA = __shfl(t, 0), tB = __shfl(t, 63);
  if (tA == tB){
    unsigned long long m = __ballot(pred);
    int total = __popcll(m);
    int base = 0;
    if (lane == 0 && total > 0) base = atomicAdd(nz + tA, total);
    base = __shfl(base, 0);
    if (pred){
      int myoff = __popcll(m & ((1ULL << lane) - 1ULL));
      zAll[(size_t)tA*NN + base + myoff] = d;
    }
  } else {
    if (pred){
      int pp = atomicAdd(nz + t, 1);
      zAll[(size_t)t*NN + pp] = d;
    }
  }
}

// per-relation mean of h rows (bf16 out)
__global__ __launch_bounds__(256) void rmean_k(const int* __restrict__ startT, const int* __restrict__ rnode,
    const bf16_t* __restrict__ hb, bf16_t* __restrict__ meanb, int rbase){
  int r = blockIdx.x, c = threadIdx.x;
  int s0 = startT[r] - rbase, s1 = startT[r+1] - rbase;
  float acc = 0.f, acc2 = 0.f;
  int i = s0;
  for (; i + 1 < s1; i += 2){
    acc  += (float)hb[(size_t)rnode[i]*HH + c];
    acc2 += (float)hb[(size_t)rnode[i+1]*HH + c];
  }
  if (i < s1) acc += (float)hb[(size_t)rnode[i]*HH + c];
  acc += acc2;
  int cnt = s1 - s0;
  meanb[(size_t)r*HH + c] = (bf16_t)((cnt > 0) ? acc/(float)cnt : 0.f);
}

// ---------------- GRU gates + row l2norm, in-place h0 (f32) + bf16 shadow ----------------
__global__ __launch_bounds__(256) void gru_gate_k(const float* __restrict__ gi,
    const float* __restrict__ ghb, float* __restrict__ h0, bf16_t* __restrict__ h0b){
  int r = blockIdx.x, c = threadIdx.x;
  float ir = gi[(size_t)r*768 + c],       hr = ghb[(size_t)r*768 + c];
  float iz = gi[(size_t)r*768 + 256 + c], hz = ghb[(size_t)r*768 + 256 + c];
  float in_ = gi[(size_t)r*768 + 512 + c], hn = ghb[(size_t)r*768 + 512 + c];
  float rg = sigm(ir + hr);
  float z  = sigm(iz + hz);
  float n  = tanhf(in_ + rg*hn);
  float hp = h0[(size_t)r*HH + c];
  float v = (1.f - z)*n + z*hp;
  float ss = v*v;
  #pragma unroll
  for (int o=32;o;o>>=1) ss += __shfl_down(ss, o);
  __shared__ float red[4];
  if ((threadIdx.x & 63)==0) red[threadIdx.x>>6] = ss;
  __syncthreads();
  float tot = red[0]+red[1]+red[2]+red[3];
  float nv = v / fmaxf(sqrtf(tot), 1e-12f);
  h0[(size_t)r*HH + c] = nv;
  h0b[(size_t)r*HH + c] = (bf16_t)nv;
}

// ---------------- gather mean messages (packed u32 edge payload, unrolled x2) ----------------
__global__ __launch_bounds__(256) void gatherM_k(const bf16_t* __restrict__ nin,
    const bf16_t* __restrict__ h0b, const int* __restrict__ startT,
    const unsigned* __restrict__ dpack, bf16_t* __restrict__ Amean, int ebase){
  int w = threadIdx.x >> 6, ln = threadIdx.x & 63;
  int d = blockIdx.x*4 + w;
  if (d >= NN) return;
  int s0 = startT[RR + d] - ebase, s1 = startT[RR + d + 1] - ebase;
  int deg = s1 - s0;
  float a0=0.f, a1=0.f, a2=0.f, a3=0.f;
  int i = s0;
  for (; i + 1 < s1; i += 2){
    unsigned seA = dpack[i], seB = dpack[i+1];
    uint2 raA = *(const uint2*)(nin + (size_t)(seA & 0xffffu)*HH + ln*4);
    uint2 raB = *(const uint2*)(nin + (size_t)(seB & 0xffffu)*HH + ln*4);
    uint2 rbA = *(const uint2*)(h0b + (size_t)(seA >> 16)*HH + ln*4);
    uint2 rbB = *(const uint2*)(h0b + (size_t)(seB >> 16)*HH + ln*4);
    a0 += __uint_as_float((raA.x & 0xffffu) << 16) + __uint_as_float((rbA.x & 0xffffu) << 16)
        + __uint_as_float((raB.x & 0xffffu) << 16) + __uint_as_float((rbB.x & 0xffffu) << 16);
    a1 += __uint_as_float(raA.x & 0xffff0000u)     + __uint_as_float(rbA.x & 0xffff0000u)
        + __uint_as_float(raB.x & 0xffff0000u)     + __uint_as_float(rbB.x & 0xffff0000u);
    a2 += __uint_as_float((raA.y & 0xffffu) << 16) + __uint_as_float((rbA.y & 0xffffu) << 16)
        + __uint_as_float((raB.y & 0xffffu) << 16) + __uint_as_float((rbB.y & 0xffffu) << 16);
    a3 += __uint_as_float(raA.y & 0xffff0000u)     + __uint_as_float(rbA.y & 0xffff0000u)
        + __uint_as_float(raB.y & 0xffff0000u)     + __uint_as_float(rbB.y & 0xffff0000u);
  }
  if (i < s1){
    unsigned se = dpack[i];
    uint2 ra = *(const uint2*)(nin + (size_t)(se & 0xffffu)*HH + ln*4);
    uint2 rb = *(const uint2*)(h0b + (size_t)(se >> 16)*HH + ln*4);
    a0 += __uint_as_float((ra.x & 0xffffu) << 16) + __uint_as_float((rb.x & 0xffffu) << 16);
    a1 += __uint_as_float(ra.x & 0xffff0000u)     + __uint_as_float(rb.x & 0xffff0000u);
    a2 += __uint_as_float((ra.y & 0xffffu) << 16) + __uint_as_float((rb.y & 0xffffu) << 16);
    a3 += __uint_as_float(ra.y & 0xffff0000u)     + __uint_as_float(rb.y & 0xffff0000u);
  }
  float inv = (deg > 0) ? 1.f/(float)deg : 0.f;
  bf16_t m[4] = { (bf16_t)(a0*inv), (bf16_t)(a1*inv), (bf16_t)(a2*inv), (bf16_t)(a3*inv) };
  *(uint2*)(Amean + (size_t)d*HH + ln*4) = *(const uint2*)m;
}

// ---------------- fused l2norm(nh2_bf) + time-gate h update (bf16 state, in-place, same-thread) ----------------
__global__ __launch_bounds__(256) void l2up_k(const bf16_t* __restrict__ nh2b, const bf16_t* __restrict__ sg,
    bf16_t* __restrict__ hb){
  int i = blockIdx.x, c = threadIdx.x;
  size_t idx = (size_t)i*HH + c;
  float v = (float)nh2b[idx];
  float ss = v*v;
  #pragma unroll
  for (int o=32;o;o>>=1) ss += __shfl_down(ss, o);
  __shared__ float red[4];
  if ((threadIdx.x & 63)==0) red[threadIdx.x>>6] = ss;
  __syncthreads();
  float tot = red[0]+red[1]+red[2]+red[3];
  float curn = v / fmaxf(sqrtf(tot), 1e-12f);
  float s = (float)sg[idx];
  float hn = s*curn + (1.f-s)*(float)hb[idx];
  hb[idx] = (bf16_t)hn;
}

extern "C" void kernel_launch(void* const* d_in, const int* in_sizes, int n_in,
                              void* d_out, int out_size, void* d_ws, size_t ws_size,
                              hipStream_t stream) {
  const int*   src     = (const int*)  d_in[0];
  const int*   dst     = (const int*)  d_in[1];
  const int*   etype   = (const int*)  d_in[2];
  const int*   r_to_e  = (const int*)  d_in[3];
  const int*   r_seg   = (const int*)  d_in[4];
  const float* pos_enc = (const float*)d_in[5];
  const float* dyn_emb = (const float*)d_in[6];
  const float* emb_rel = (const float*)d_in[7];
  const float* gW_ih   = (const float*)d_in[8];
  const float* gW_hh   = (const float*)d_in[9];
  const float* gb_ih   = (const float*)d_in[10];
  const float* gb_hh   = (const float*)d_in[11];
  const float* W_neigh = (const float*)d_in[12];
  const float* W_loop  = (const float*)d_in[13];
  const float* W_evolve= (const float*)d_in[14];
  const float* W_hp    = (const float*)d_in[15];
  const float* b_hp    = (const float*)d_in[16];
  const float* W_v     = (const float*)d_in[17];
  const float* b_v     = (const float*)d_in[18];
  const float* W_o     = (const float*)d_in[19];
  const float* b_o     = (const float*)d_in[20];
  const float* time_W  = (const float*)d_in[21];
  const float* time_b  = (const float*)d_in[22];
  const float* glob_W  = (const float*)d_in[23];
  const float* glob_b  = (const float*)d_in[24];
  float* out = (float*)d_out;
  (void)in_sizes; (void)n_in; (void)out_size; (void)ws_size;

  char* ws = (char*)d_ws;
  size_t off = 0;
  auto allocB = [&](size_t bytes)->char*{
    char* pp = ws + off; off += (bytes + 255) & ~(size_t)255;
    return pp;
  };
  float*  tmp    = (float*) allocB(NHf*4);          // Amean (bf16, 1st half) + sgate (bf16, 2nd half)
  bf16_t* h_bf   = (bf16_t*)allocB(NHf*2);          // recurrent state (bf16)
  bf16_t* nh_bf  = (bf16_t*)allocB(NHf*2);          // layer-0 out; aliased: attn_bf
  bf16_t* nh2_bf = (bf16_t*)allocB(NHf*2);
  bf16_t* gh_bf  = (bf16_t*)allocB(NHf*2);
  bf16_t* Amean  = (bf16_t*)tmp;
  bf16_t* sgate  = (bf16_t*)(tmp + NHf/2);
  bf16_t* attn_bf= nh_bf;

  float*  h0    = (float*) allocB((size_t)RR*HH*4);
  bf16_t* h0b   = (bf16_t*)allocB((size_t)RR*HH*2);
  bf16_t* meanb = (bf16_t*)allocB((size_t)RR*HH*2);
  float*  gi0   = (float*) allocB((size_t)RR*768*4);
  float*  gi    = (float*) allocB((size_t)RR*768*4);
  float*  ghb   = (float*) allocB((size_t)RR*768*4);
  bf16_t* wihAT = (bf16_t*)allocB((size_t)768*256*2);
  bf16_t* wihBT = (bf16_t*)allocB((size_t)768*256*2);
  bf16_t* whhT  = (bf16_t*)allocB((size_t)768*256*2);
  float*  WP    = (float*) allocB((size_t)PP*HH*4);
  float*  WovF  = (float*) allocB((size_t)HH*HH*4);
  float*  b_ov  = (float*) allocB((size_t)HH*4);
  bf16_t* bst2  = (bf16_t*)allocB((size_t)2*HH*512*2);   // per-layer [Wn|Wl]^T, ld 512
  bf16_t* wdT   = (bf16_t*)allocB((size_t)2*HH*HH*2);    // per-layer (We-Wl)^T
  bf16_t* whpT  = (bf16_t*)allocB((size_t)HH*HH*2);
  bf16_t* wovT  = (bf16_t*)allocB((size_t)HH*HH*2);
  bf16_t* timT  = (bf16_t*)allocB((size_t)HH*HH*2);
  bf16_t* globT = (bf16_t*)allocB((size_t)HH*HH*2);
  int* cnt    = (int*)allocB((size_t)(NBIN3+4)*4);       // + nz[3] at tail
  int* start  = (int*)allocB((size_t)(NBIN3+1)*4);
  int* cur    = (int*)allocB((size_t)NBIN3*4);
  int* rnode  = (int*)allocB((size_t)3*EE*4);
  unsigned* dpack = (unsigned*)allocB((size_t)3*EE*4);
  int* zAll   = (int*)allocB((size_t)3*NN*4);
  int* bsum   = (int*)allocB(256*4);
  int* boff   = (int*)allocB(256*4);
  int* nz     = cnt + NBIN3;

  const int MT2 = (NN + 63)/64;              // 782 row tiles (BM=64)
  const int NB3 = (NBIN3 + 1023)/1024;       // 148 scan blocks

  // ---- setup: weight prep + initial h/h0 + gi0 ----
  copyall_k<<<dim3(768,5), 256, 0, stream>>>(gW_ih, gW_hh, W_hp, emb_rel,
                                             wihAT, wihBT, whhT, whpT, h0b);
  tconv_all_k<<<dim3(8,8,8), 256, 0, stream>>>(W_neigh, W_loop, W_evolve, time_W, glob_W,
                                               bst2, wdT, timT, globT);
  misc_k<<<2, 256, 0, stream>>>(W_hp, WP, W_o, b_v, b_o, b_ov);
  sgemm_k<<<dim3(2,4), 256, 0, stream>>>(W_o, W_v, WovF, 256, 256, 256);
  copy_bfw_k<<<HH, 256, 0, stream>>>(WovF, wovT);
  l2norm_k<<<NN, 256, 0, stream>>>(dyn_emb, h_bf);
  hipMemcpyAsync(h0, emb_rel, (size_t)RR*HH*4, hipMemcpyDeviceToDevice, stream);
  // gi0 = emb_rel @ W_ih[:, :256]^T + b_ih   (h0b == emb_rel bf16 at this point)
  mgemm_k<0,1><<<dim3(4,6), 256, 0, stream>>>(h0b, wihAT, gi0, gb_ih, RR, 768, 256, nullptr);

  // ---- batched CSR build for all 3 snapshots ----
  hipMemsetAsync(cnt, 0, (size_t)(NBIN3+4)*4, stream);
  hist3_k<<<(6*EE+255)/256, 256, 0, stream>>>(r_seg, dst, cnt);
  scan1_k<<<NB3, 1024, 0, stream>>>(cnt, start, bsum, NBIN3);
  scan2_k<<<1, 256, 0, stream>>>(bsum, boff, start, NB3, NBIN3);
  scan3_k<<<NB3, 1024, 0, stream>>>(start, cur, boff, NBIN3);
  fill3_k<<<(6*EE+255)/256, 256, 0, stream>>>(r_seg, r_to_e, dst, src, etype, cur, rnode, dpack);
  compact3_k<<<(3*NN+255)/256, 256, 0, stream>>>(cnt, zAll, nz);

  for (int t=0; t<TT; t++){
    const float* posT = pos_enc + (size_t)t*NN*PP;
    const int* startT = start + (size_t)t*NBIN;
    const int* degT   = cnt + (size_t)t*NBIN + RR;
    const int* zT     = zAll + (size_t)t*NN;
    const int* nzT    = nz + t;

    // ---- relation mean + GRU ----
    rmean_k<<<RR, 256, 0, stream>>>(startT, rnode, h_bf, meanb, EE*t);
    mgemm_k<8,0><<<dim3(4,6), 256, 0, stream>>>(meanb, wihBT, gi, nullptr, RR, 768, 256, gi0);
    mgemm_k<0,1><<<dim3(4,6), 256, 0, stream>>>(h0b, whhT, ghb, gb_hh, RR, 768, 256, nullptr);
    gru_gate_k<<<RR, 256, 0, stream>>>(gi, ghb, h0, h0b);

    // ---- RGCN layer 0 ----
    gatherM_k<<<(NN+3)/4, 256, 0, stream>>>(h_bf, h0b, startT, dpack, Amean, EE*(t+1));
    mgemm2_k<4,0,1,0,1><<<MT2, 512, 0, stream>>>(Amean, h_bf, bst2, nullptr, nh_bf, nullptr,
        NN, 512, nullptr, nullptr, nullptr, nullptr, degT, nullptr, nullptr);
    mgemm2_k<5,0,1,0,0><<<MT2, 512, 0, stream>>>(h_bf, nullptr, wdT, nullptr, nh_bf, nullptr,
        NN, 256, nullptr, nullptr, nullptr, nullptr, nullptr, zT, nzT);

    // ---- RGCN layer 1 ----
    gatherM_k<<<(NN+3)/4, 256, 0, stream>>>(nh_bf, h0b, startT, dpack, Amean, EE*(t+1));
    mgemm2_k<4,0,1,0,1><<<MT2, 512, 0, stream>>>(Amean, nh_bf, bst2 + (size_t)HH*512, nullptr, nh2_bf, nullptr,
        NN, 512, nullptr, nullptr, nullptr, nullptr, degT, nullptr, nullptr);
    mgemm2_k<5,0,1,0,0><<<MT2, 512, 0, stream>>>(nh_bf, nullptr, wdT + (size_t)HH*HH, nullptr, nh2_bf, nullptr,
        NN, 256, nullptr, nullptr, nullptr, nullptr, nullptr, zT, nzT);

    // ---- attention chain ----
    mgemm2_k<2,0,1,1,0><<<MT2, 512, 0, stream>>>(nh2_bf, nullptr, whpT, nullptr, attn_bf, b_hp,
        NN, 256, posT, WP, nullptr, nullptr, nullptr, nullptr, nullptr);
    mgemm2_k<0,0,1,1,0><<<MT2, 512, 0, stream>>>(attn_bf, nullptr, wovT, nullptr, gh_bf, b_ov,
        NN, 256, nullptr, nullptr, nullptr, nullptr, nullptr, nullptr, nullptr);

    // ---- time gate (sigmoid in epilogue, bf16), fused norm+update (in-place bf16 h), glob+blend ----
    mgemm2_k<7,0,1,1,0><<<MT2, 512, 0, stream>>>(h_bf, nullptr, timT, nullptr, sgate, time_b,
        NN, 256, nullptr, nullptr, nullptr, nullptr, nullptr, nullptr, nullptr);
    l2up_k<<<NN, 256, 0, stream>>>(nh2_bf, sgate, h_bf);
    mgemm2_k<3,1,0,1,0><<<MT2, 512, 0, stream>>>(h_bf, nullptr, globT, out + (size_t)t*NHf, nullptr, glob_b,
        NN, 256, nullptr, nullptr, gh_bf, h_bf, nullptr, nullptr, nullptr);
  }
}

// Round 14
// 1220.297 us; speedup vs baseline: 1.3456x; 1.0894x over previous
//
#include <hip/hip_runtime.h>
#include <math.h>

#define NN 50000
#define HH 256
#define RR 460
#define TT 3
#define EE 100000
#define PP 3
#define SLOPE 0.22916666666666666f
#define NBIN (RR + NN)           // per-t bins: 50460
#define NBIN3 (3*NBIN)           // batched bins

typedef __bf16 bf16_t;
typedef bf16_t bf16x8 __attribute__((ext_vector_type(8)));
typedef float f32x4 __attribute__((ext_vector_type(4)));

static const size_t NHf = (size_t)NN * HH;   // 12.8M elements

__device__ __forceinline__ float sigm(float x){ return 1.0f/(1.0f+__expf(-x)); }
__device__ __forceinline__ float leaky(float x){ return (x >= 0.f) ? x : SLOPE*x; }

__device__ __forceinline__ void gload_lds16(const void* g, void* l){
  __builtin_amdgcn_global_load_lds((const __attribute__((address_space(1))) void*)g,
                                   (__attribute__((address_space(3))) void*)l, 16, 0, 0);
}

// ---------------- merged weight transposes: 8 jobs via blockIdx.z ----------------
// bst3 per layer: [256 out][768 K] = [Wn^T | Wl^T | (We-Wl)^T]
__global__ __launch_bounds__(256) void tconv_all_k(
    const float* __restrict__ Wn, const float* __restrict__ Wl, const float* __restrict__ We,
    const float* __restrict__ timW, const float* __restrict__ globW,
    bf16_t* __restrict__ bst3, bf16_t* __restrict__ timT, bf16_t* __restrict__ globT){
  int z = blockIdx.z;
  const float* in; const float* in2 = nullptr; bf16_t* outp; int ldout;
  switch(z){
    case 0: in = Wn;          outp = bst3;                          ldout = 768; break;
    case 1: in = Wl;          outp = bst3 + 256;                    ldout = 768; break;
    case 2: in = We;         in2 = Wl;         outp = bst3 + 512;   ldout = 768; break;
    case 3: in = Wn + 65536;  outp = bst3 + (size_t)256*768;        ldout = 768; break;
    case 4: in = Wl + 65536;  outp = bst3 + (size_t)256*768 + 256;  ldout = 768; break;
    case 5: in = We + 65536; in2 = Wl + 65536; outp = bst3 + (size_t)256*768 + 512; ldout = 768; break;
    case 6: in = timW;  outp = timT;  ldout = 256; break;
    default:in = globW; outp = globT; ldout = 256; break;
  }
  __shared__ float tile[32][33];
  int n0 = blockIdx.x*32, k0 = blockIdx.y*32;
  int tx = threadIdx.x & 31, ty = threadIdx.x >> 5;
  #pragma unroll
  for (int j=0;j<4;j++){
    size_t idx = (size_t)(k0+ty+j*8)*256 + n0+tx;
    float v = in[idx];
    if (in2) v -= in2[idx];
    tile[ty+j*8][tx] = v;
  }
  __syncthreads();
  #pragma unroll
  for (int j=0;j<4;j++)
    outp[(size_t)(n0+ty+j*8)*ldout + k0+tx] = (bf16_t)tile[tx][ty+j*8];
}

// ---------------- merged row copy+convert jobs via blockIdx.y ----------------
__global__ __launch_bounds__(256) void copyall_k(const float* __restrict__ gW_ih,
    const float* __restrict__ gW_hh, const float* __restrict__ W_hp, const float* __restrict__ emb_rel,
    bf16_t* __restrict__ wihAT, bf16_t* __restrict__ wihBT, bf16_t* __restrict__ whhT,
    bf16_t* __restrict__ whpT, bf16_t* __restrict__ h0b){
  int r = blockIdx.x, c = threadIdx.x, y = blockIdx.y;
  if (y == 0)      wihAT[(size_t)r*256+c] = (bf16_t)gW_ih[(size_t)r*512 + c];
  else if (y == 1) wihBT[(size_t)r*256+c] = (bf16_t)gW_ih[(size_t)r*512 + 256 + c];
  else if (y == 2) whhT[(size_t)r*256+c]  = (bf16_t)gW_hh[(size_t)r*256 + c];
  else if (y == 3){ if (r < 256) whpT[(size_t)r*256+c] = (bf16_t)W_hp[(size_t)r*259 + c]; }
  else            { if (r < RR)  h0b[(size_t)r*256+c]  = (bf16_t)emb_rel[(size_t)r*256 + c]; }
}

// ---------------- misc small setup: WP extract + b_ov ----------------
__global__ __launch_bounds__(256) void misc_k(const float* __restrict__ W_hp, float* __restrict__ WP,
    const float* __restrict__ W_o, const float* __restrict__ b_v, const float* __restrict__ b_o,
    float* __restrict__ b_ov){
  if (blockIdx.x == 0){
    int j = threadIdx.x;
    #pragma unroll
    for (int p=0;p<PP;p++) WP[p*HH + j] = W_hp[(size_t)j*259 + HH + p];
  } else {
    int n = threadIdx.x;
    float s = b_o[n];
    for (int j=0;j<256;j++) s += W_o[(size_t)n*256+j]*b_v[j];
    b_ov[n] = s;
  }
}

// ---------------- row copy+convert (wovT after sgemm) ----------------
__global__ __launch_bounds__(256) void copy_bfw_k(const float* __restrict__ in, bf16_t* __restrict__ outp){
  int r = blockIdx.x, c = threadIdx.x;
  outp[(size_t)r*HH + c] = (bf16_t)in[(size_t)r*HH + c];
}

// ---------------- f32 SGEMM (setup: WovF only) ----------------
__global__ __launch_bounds__(256) void sgemm_k(const float* __restrict__ A, const float* __restrict__ B,
                                               float* __restrict__ C, int M, int N, int K){
  __shared__ float As[16][128];
  __shared__ float Bs[16][64];
  int tid = threadIdx.x;
  int tx = tid & 15, ty = tid >> 4;
  int rowBase = blockIdx.x * 128;
  int colBase = blockIdx.y * 64;
  float acc[8][4];
  #pragma unroll
  for (int i=0;i<8;i++)
    #pragma unroll
    for (int j=0;j<4;j++) acc[i][j]=0.f;
  for (int k0=0;k0<K;k0+=16){
    #pragma unroll
    for (int ss=0; ss<2; ss++){
      int s = tid + ss*256;
      int r = s >> 2;
      int kk = (s & 3)*4;
      float4 v = make_float4(0.f,0.f,0.f,0.f);
      int grow = rowBase + r;
      if (grow < M) v = *(const float4*)(A + (size_t)grow*K + k0 + kk);
      As[kk+0][r]=v.x; As[kk+1][r]=v.y; As[kk+2][r]=v.z; As[kk+3][r]=v.w;
    }
    {
      int r = tid >> 4, cc = (tid & 15)*4;
      float4 v = *(const float4*)(B + (size_t)(k0+r)*N + colBase + cc);
      *(float4*)&Bs[r][cc] = v;
    }
    __syncthreads();
    #pragma unroll
    for (int kk=0;kk<16;kk++){
      float a[8], b[4];
      *(float4*)&a[0] = *(const float4*)&As[kk][ty*8];
      *(float4*)&a[4] = *(const float4*)&As[kk][ty*8+4];
      *(float4*)&b[0] = *(const float4*)&Bs[kk][tx*4];
      #pragma unroll
      for (int i=0;i<8;i++)
        #pragma unroll
        for (int j=0;j<4;j++)
          acc[i][j] = fmaf(a[i], b[j], acc[i][j]);
    }
    __syncthreads();
  }
  #pragma unroll
  for (int i=0;i<8;i++){
    int gr = rowBase + ty*8 + i;
    if (gr >= M) continue;
    float4 v = make_float4(acc[i][0], acc[i][1], acc[i][2], acc[i][3]);
    *(float4*)(C + (size_t)gr*N + colBase + tx*4) = v;
  }
}

// ---------------- bf16 MFMA GEMM, 256 threads (RR-sized GRU GEMMs, N=768) ----------------
// EPI: 0 plain(+bias); 8 v += e1-matrix.
template<int EPI, int HASB>
__global__ __launch_bounds__(256) void mgemm_k(
    const bf16_t* __restrict__ A0, const bf16_t* __restrict__ Bt,
    float* __restrict__ C, const float* __restrict__ bias,
    int M, int N, int K, const float* __restrict__ e1){
  __shared__ bf16_t As[128*64];
  __shared__ bf16_t Bs[128*64];
  int tid = threadIdx.x;
  int lane = tid & 63, w = tid >> 6;
  int wm = w >> 1, wn = w & 1;
  int rowBase = blockIdx.x * 128;
  int colBase = blockIdx.y * 128;
  f32x4 acc[4][4] = {};

  int lrow = lane >> 3;
  int p    = lane & 7;
  int arow[4];
  #pragma unroll
  for (int c = 0; c < 4; c++){
    int gr = rowBase + c*32 + w*8 + lrow;
    arow[c] = min(gr, M-1);
  }
  for (int k0 = 0; k0 < K; k0 += 64){
    #pragma unroll
    for (int c = 0; c < 4; c++){
      int r = c*32 + w*8 + lrow;
      int s = p ^ (r & 7);
      gload_lds16(A0 + (size_t)arow[c]*K + k0 + s*8, As + (size_t)(c*32 + w*8)*64);
      int gb = colBase + r;
      gload_lds16(Bt + (size_t)gb*K + k0 + s*8, Bs + (size_t)(c*32 + w*8)*64);
    }
    asm volatile("s_waitcnt vmcnt(0)" ::: "memory");
    __syncthreads();
    #pragma unroll
    for (int kk = 0; kk < 2; kk++){
      bf16x8 af[4], bfr[4];
      int sg = kk*4 + (lane >> 4);
      #pragma unroll
      for (int i = 0; i < 4; i++){
        int r = wm*64 + i*16 + (lane & 15);
        af[i] = *(const bf16x8*)(As + r*64 + (sg ^ (r & 7))*8);
      }
      #pragma unroll
      for (int j = 0; j < 4; j++){
        int rn = wn*64 + j*16 + (lane & 15);
        bfr[j] = *(const bf16x8*)(Bs + rn*64 + (sg ^ (rn & 7))*8);
      }
      #pragma unroll
      for (int i = 0; i < 4; i++)
        #pragma unroll
        for (int j = 0; j < 4; j++)
          acc[i][j] = __builtin_amdgcn_mfma_f32_16x16x32_bf16(af[i], bfr[j], acc[i][j], 0, 0, 0);
    }
    __syncthreads();
  }
  int colv[4]; float bb[4];
  #pragma unroll
  for (int j = 0; j < 4; j++){
    colv[j] = colBase + wn*64 + j*16 + (lane & 15);
    bb[j] = HASB ? bias[colv[j]] : 0.f;
  }
  #pragma unroll
  for (int i = 0; i < 4; i++){
    #pragma unroll
    for (int q = 0; q < 4; q++){
      int grt = rowBase + wm*64 + i*16 + ((lane >> 4) << 2) + q;
      if (grt >= M) continue;
      #pragma unroll
      for (int j = 0; j < 4; j++){
        size_t idx = (size_t)grt*N + colv[j];
        float v = acc[i][j][q] + bb[j];
        if (EPI == 8) v += e1[idx];
        C[idx] = v;
      }
    }
  }
}

// ---------------- bf16 MFMA GEMM, 512 threads, BM=64 BN=256 (A read once, high occupancy) ----------------
// 8 waves, wave w owns cols w*32..w*32+31; acc[4][2].
// SPLITA: 0 = contiguous A (lda=K); 2 = K=768 3-segment: k<256 from A0 (Amean, lda256),
//         256..511 from A1 (nh, lda256), >=512 per-row conditional: deg==0 ? A1-row : zero-row.
// EPI: 0 plain(+bias)->Cb; 2 tanh(v+pos+bias)->Cb [e1=pos, e2=WP]; 3 gate-blend->C f32:
//      g=sigm(v+bias), C=g*eb+(1-g)*eb2; 6 leaky(v)->Cb; 7 sigm(v+bias)->Cb.
template<int EPI, int WF32, int WBF, int HASB, int SPLITA>
__global__ __launch_bounds__(512, 6) void mgemm2_k(
    const bf16_t* __restrict__ A0, const bf16_t* __restrict__ A1,
    const bf16_t* __restrict__ Bt,
    float* __restrict__ C, bf16_t* __restrict__ Cb, const float* __restrict__ bias,
    int M, int K,
    const float* __restrict__ e1, const float* __restrict__ e2,
    const bf16_t* __restrict__ eb, const bf16_t* __restrict__ eb2,
    const int* __restrict__ degp, const bf16_t* __restrict__ zrow){
  int rowBase = blockIdx.x * 64;
  __shared__ bf16_t As[64*64];    // 8 KB
  __shared__ bf16_t Bs[256*64];   // 32 KB
  int tid = threadIdx.x;
  int lane = tid & 63, w = tid >> 6;       // w 0..7 = wn
  f32x4 acc[4][2] = {};

  int lrow8 = lane >> 3;          // 0..7
  int p     = lane & 7;           // phys 16B seg
  int arow;
  const bf16_t* a2base = nullptr;
  {
    int r = w*8 + lrow8;
    arow = min(rowBase + r, M-1);
    if (SPLITA == 2) a2base = (degp[arow] == 0) ? (A1 + (size_t)arow*256) : zrow;
  }
  for (int k0 = 0; k0 < K; k0 += 64){
    const bf16_t* Ap; int koff;
    if (SPLITA == 2){
      Ap = (k0 < 256) ? (A0 + (size_t)arow*256)
         : (k0 < 512) ? (A1 + (size_t)arow*256)
         : a2base;
      koff = k0 & 255;
    } else {
      Ap = A0 + (size_t)arow*K; koff = k0;
    }
    {
      int r = w*8 + lrow8;
      int s = p ^ (r & 7);                 // both-sides swizzle
      gload_lds16(Ap + koff + s*8, As + (size_t)(w*8)*64);
    }
    #pragma unroll
    for (int c = 0; c < 4; c++){
      int r = w*32 + c*8 + lrow8;          // 0..255
      int s = p ^ (r & 7);
      gload_lds16(Bt + (size_t)r*K + k0 + s*8, Bs + (size_t)(w*32 + c*8)*64);
    }
    asm volatile("s_waitcnt vmcnt(0)" ::: "memory");
    __syncthreads();
    #pragma unroll
    for (int kk = 0; kk < 2; kk++){
      bf16x8 af[4], bfr[2];
      int sg = kk*4 + (lane >> 4);         // logical seg 0..7
      #pragma unroll
      for (int i = 0; i < 4; i++){
        int r = i*16 + (lane & 15);
        af[i] = *(const bf16x8*)(As + r*64 + (sg ^ (r & 7))*8);
      }
      #pragma unroll
      for (int j = 0; j < 2; j++){
        int rn = w*32 + j*16 + (lane & 15);
        bfr[j] = *(const bf16x8*)(Bs + rn*64 + (sg ^ (rn & 7))*8);
      }
      #pragma unroll
      for (int i = 0; i < 4; i++)
        #pragma unroll
        for (int j = 0; j < 2; j++)
          acc[i][j] = __builtin_amdgcn_mfma_f32_16x16x32_bf16(af[i], bfr[j], acc[i][j], 0, 0, 0);
    }
    __syncthreads();
  }
  // ---- epilogue (N = 256) ----
  int colv[2]; float bb[2], wp0[2], wp1[2], wp2[2];
  #pragma unroll
  for (int j = 0; j < 2; j++){
    colv[j] = w*32 + j*16 + (lane & 15);
    bb[j] = HASB ? bias[colv[j]] : 0.f;
    if (EPI == 2){ wp0[j] = e2[colv[j]]; wp1[j] = e2[256+colv[j]]; wp2[j] = e2[512+colv[j]]; }
  }
  #pragma unroll
  for (int i = 0; i < 4; i++){
    #pragma unroll
    for (int q = 0; q < 4; q++){
      int grt = rowBase + i*16 + ((lane >> 4) << 2) + q;
      if (grt >= M) continue;
      float p0=0.f, p1=0.f, p2=0.f;
      if (EPI == 2){ p0 = e1[(size_t)grt*3]; p1 = e1[(size_t)grt*3+1]; p2 = e1[(size_t)grt*3+2]; }
      #pragma unroll
      for (int j = 0; j < 2; j++){
        size_t idx = (size_t)grt*256 + colv[j];
        float v = acc[i][j][q] + bb[j];
        if (EPI == 2) v = tanhf(v + p0*wp0[j] + p1*wp1[j] + p2*wp2[j]);
        if (EPI == 3){
          float g = sigm(v);
          v = g*(float)eb[idx] + (1.f-g)*(float)eb2[idx];
        }
        if (EPI == 6) v = leaky(v);
        if (EPI == 7) v = sigm(v);
        if (WF32) C[idx] = v;
        if (WBF)  Cb[idx] = (bf16_t)v;
      }
    }
  }
}

// ---------------- row-wise L2 normalize -> bf16 (setup) ----------------
__global__ __launch_bounds__(256) void l2norm_k(const float* __restrict__ in, bf16_t* __restrict__ outb){
  int i = blockIdx.x, c = threadIdx.x;
  size_t idx = (size_t)i*HH + c;
  float v = in[idx];
  float ss = v*v;
  #pragma unroll
  for (int o=32;o;o>>=1) ss += __shfl_down(ss, o);
  __shared__ float red[4];
  if ((threadIdx.x & 63)==0) red[threadIdx.x>>6] = ss;
  __syncthreads();
  float tot = red[0]+red[1]+red[2]+red[3];
  outb[idx] = (bf16_t)(v / fmaxf(sqrtf(tot), 1e-12f));
}

// ---------------- batched combined histogram over all 3 t's ----------------
__global__ __launch_bounds__(256) void hist3_k(const int* __restrict__ r_seg, const int* __restrict__ dst,
                                               int* __restrict__ cnt){
  int q = blockIdx.x*256 + threadIdx.x;
  if (q >= 3*2*EE) return;
  int t = q / (2*EE);
  int e = q - t*2*EE;
  if (e < EE) atomicAdd(cnt + t*NBIN + r_seg[(size_t)t*EE + e], 1);
  else        atomicAdd(cnt + t*NBIN + RR + dst[(size_t)t*EE + (e-EE)], 1);
}

// ---------------- hierarchical exclusive scan ----------------
__global__ __launch_bounds__(1024) void scan1_k(const int* __restrict__ cnt, int* __restrict__ start,
                                                int* __restrict__ bsum, int n){
  __shared__ int s[1024];
  int t = blockIdx.x*1024 + threadIdx.x;
  int v = (t < n) ? cnt[t] : 0;
  s[threadIdx.x] = v;
  __syncthreads();
  for (int off = 1; off < 1024; off <<= 1){
    int x = (threadIdx.x >= off) ? s[threadIdx.x - off] : 0;
    __syncthreads();
    s[threadIdx.x] += x;
    __syncthreads();
  }
  if (t < n) start[t] = s[threadIdx.x] - v;
  if (threadIdx.x == 1023) bsum[blockIdx.x] = s[1023];
}
__global__ __launch_bounds__(256) void scan2_k(const int* __restrict__ bsum, int* __restrict__ boff,
                                               int* __restrict__ start, int nb, int n){
  __shared__ int s[256];
  int t = threadIdx.x;
  int v = (t < nb) ? bsum[t] : 0;
  s[t] = v;
  __syncthreads();
  for (int off = 1; off < 256; off <<= 1){
    int x = (t >= off) ? s[t-off] : 0;
    __syncthreads();
    s[t] += x;
    __syncthreads();
  }
  if (t < nb) boff[t] = s[t] - v;
  if (t == 255) start[n] = s[255];
}
__global__ __launch_bounds__(1024) void scan3_k(int* __restrict__ start, int* __restrict__ cur,
                                                const int* __restrict__ boff, int n){
  int t = blockIdx.x*1024 + threadIdx.x;
  if (t < n){
    int v = start[t] + boff[blockIdx.x];
    start[t] = v;
    cur[t] = v;
  }
}

// ---------------- batched CSR fill (dst side packs src|ety<<16 into u32) ----------------
__global__ __launch_bounds__(256) void fill3_k(const int* __restrict__ r_seg, const int* __restrict__ r_to_e,
    const int* __restrict__ dst, const int* __restrict__ src, const int* __restrict__ ety,
    int* __restrict__ cur, int* __restrict__ rnode, unsigned* __restrict__ dpack){
  int q = blockIdx.x*256 + threadIdx.x;
  if (q >= 3*2*EE) return;
  int t = q / (2*EE);
  int e = q - t*2*EE;
  if (e < EE){
    size_t ge = (size_t)t*EE + e;
    int pp = atomicAdd(cur + t*NBIN + r_seg[ge], 1);
    rnode[pp - EE*t] = r_to_e[ge];
  } else {
    size_t ge = (size_t)t*EE + (e - EE);
    int pp = atomicAdd(cur + t*NBIN + RR + dst[ge], 1);
    dpack[pp - EE*(t+1)] = (unsigned)src[ge] | ((unsigned)ety[ge] << 16);
  }
}

// per-relation mean of h rows (bf16 out)
__global__ __launch_bounds__(256) void rmean_k(const int* __restrict__ startT, const int* __restrict__ rnode,
    const bf16_t* __restrict__ hb, bf16_t* __restrict__ meanb, int rbase){
  int r = blockIdx.x, c = threadIdx.x;
  int s0 = startT[r] - rbase, s1 = startT[r+1] - rbase;
  float acc = 0.f, acc2 = 0.f;
  int i = s0;
  for (; i + 1 < s1; i += 2){
    acc  += (float)hb[(size_t)rnode[i]*HH + c];
    acc2 += (float)hb[(size_t)rnode[i+1]*HH + c];
  }
  if (i < s1) acc += (float)hb[(size_t)rnode[i]*HH + c];
  acc += acc2;
  int cnt = s1 - s0;
  meanb[(size_t)r*HH + c] = (bf16_t)((cnt > 0) ? acc/(float)cnt : 0.f);
}

// ---------------- GRU gates + row l2norm, in-place h0 (f32) + bf16 shadow ----------------
__global__ __launch_bounds__(256) void gru_gate_k(const float* __restrict__ gi,
    const float* __restrict__ ghb, float* __restrict__ h0, bf16_t* __restrict__ h0b){
  int r = blockIdx.x, c = threadIdx.x;
  float ir = gi[(size_t)r*768 + c],       hr = ghb[(size_t)r*768 + c];
  float iz = gi[(size_t)r*768 + 256 + c], hz = ghb[(size_t)r*768 + 256 + c];
  float in_ = gi[(size_t)r*768 + 512 + c], hn = ghb[(size_t)r*768 + 512 + c];
  float rg = sigm(ir + hr);
  float z  = sigm(iz + hz);
  float n  = tanhf(in_ + rg*hn);
  float hp = h0[(size_t)r*HH + c];
  float v = (1.f - z)*n + z*hp;
  float ss = v*v;
  #pragma unroll
  for (int o=32;o;o>>=1) ss += __shfl_down(ss, o);
  __shared__ float red[4];
  if ((threadIdx.x & 63)==0) red[threadIdx.x>>6] = ss;
  __syncthreads();
  float tot = red[0]+red[1]+red[2]+red[3];
  float nv = v / fmaxf(sqrtf(tot), 1e-12f);
  h0[(size_t)r*HH + c] = nv;
  h0b[(size_t)r*HH + c] = (bf16_t)nv;
}

// ---------------- gather mean messages (packed u32 edge payload, unrolled x2) ----------------
__global__ __launch_bounds__(256) void gatherM_k(const bf16_t* __restrict__ nin,
    const bf16_t* __restrict__ h0b, const int* __restrict__ startT,
    const unsigned* __restrict__ dpack, bf16_t* __restrict__ Amean, int ebase){
  int w = threadIdx.x >> 6, ln = threadIdx.x & 63;
  int d = blockIdx.x*4 + w;
  if (d >= NN) return;
  int s0 = startT[RR + d] - ebase, s1 = startT[RR + d + 1] - ebase;
  int deg = s1 - s0;
  float a0=0.f, a1=0.f, a2=0.f, a3=0.f;
  int i = s0;
  for (; i + 1 < s1; i += 2){
    unsigned seA = dpack[i], seB = dpack[i+1];
    uint2 raA = *(const uint2*)(nin + (size_t)(seA & 0xffffu)*HH + ln*4);
    uint2 raB = *(const uint2*)(nin + (size_t)(seB & 0xffffu)*HH + ln*4);
    uint2 rbA = *(const uint2*)(h0b + (size_t)(seA >> 16)*HH + ln*4);
    uint2 rbB = *(const uint2*)(h0b + (size_t)(seB >> 16)*HH + ln*4);
    a0 += __uint_as_float((raA.x & 0xffffu) << 16) + __uint_as_float((rbA.x & 0xffffu) << 16)
        + __uint_as_float((raB.x & 0xffffu) << 16) + __uint_as_float((rbB.x & 0xffffu) << 16);
    a1 += __uint_as_float(raA.x & 0xffff0000u)     + __uint_as_float(rbA.x & 0xffff0000u)
        + __uint_as_float(raB.x & 0xffff0000u)     + __uint_as_float(rbB.x & 0xffff0000u);
    a2 += __uint_as_float((raA.y & 0xffffu) << 16) + __uint_as_float((rbA.y & 0xffffu) << 16)
        + __uint_as_float((raB.y & 0xffffu) << 16) + __uint_as_float((rbB.y & 0xffffu) << 16);
    a3 += __uint_as_float(raA.y & 0xffff0000u)     + __uint_as_float(rbA.y & 0xffff0000u)
        + __uint_as_float(raB.y & 0xffff0000u)     + __uint_as_float(rbB.y & 0xffff0000u);
  }
  if (i < s1){
    unsigned se = dpack[i];
    uint2 ra = *(const uint2*)(nin + (size_t)(se & 0xffffu)*HH + ln*4);
    uint2 rb = *(const uint2*)(h0b + (size_t)(se >> 16)*HH + ln*4);
    a0 += __uint_as_float((ra.x & 0xffffu) << 16) + __uint_as_float((rb.x & 0xffffu) << 16);
    a1 += __uint_as_float(ra.x & 0xffff0000u)     + __uint_as_float(rb.x & 0xffff0000u);
    a2 += __uint_as_float((ra.y & 0xffffu) << 16) + __uint_as_float((rb.y & 0xffffu) << 16);
    a3 += __uint_as_float(ra.y & 0xffff0000u)     + __uint_as_float(rb.y & 0xffff0000u);
  }
  float inv = (deg > 0) ? 1.f/(float)deg : 0.f;
  bf16_t m[4] = { (bf16_t)(a0*inv), (bf16_t)(a1*inv), (bf16_t)(a2*inv), (bf16_t)(a3*inv) };
  *(uint2*)(Amean + (size_t)d*HH + ln*4) = *(const uint2*)m;
}

// ---------------- fused l2norm(nh2_bf) + time-gate h update (bf16 state, in-place, same-thread) ----------------
__global__ __launch_bounds__(256) void l2up_k(const bf16_t* __restrict__ nh2b, const bf16_t* __restrict__ sg,
    bf16_t* __restrict__ hb){
  int i = blockIdx.x, c = threadIdx.x;
  size_t idx = (size_t)i*HH + c;
  float v = (float)nh2b[idx];
  float ss = v*v;
  #pragma unroll
  for (int o=32;o;o>>=1) ss += __shfl_down(ss, o);
  __shared__ float red[4];
  if ((threadIdx.x & 63)==0) red[threadIdx.x>>6] = ss;
  __syncthreads();
  float tot = red[0]+red[1]+red[2]+red[3];
  float curn = v / fmaxf(sqrtf(tot), 1e-12f);
  float s = (float)sg[idx];
  float hn = s*curn + (1.f-s)*(float)hb[idx];
  hb[idx] = (bf16_t)hn;
}

extern "C" void kernel_launch(void* const* d_in, const int* in_sizes, int n_in,
                              void* d_out, int out_size, void* d_ws, size_t ws_size,
                              hipStream_t stream) {
  const int*   src     = (const int*)  d_in[0];
  const int*   dst     = (const int*)  d_in[1];
  const int*   etype   = (const int*)  d_in[2];
  const int*   r_to_e  = (const int*)  d_in[3];
  const int*   r_seg   = (const int*)  d_in[4];
  const float* pos_enc = (const float*)d_in[5];
  const float* dyn_emb = (const float*)d_in[6];
  const float* emb_rel = (const float*)d_in[7];
  const float* gW_ih   = (const float*)d_in[8];
  const float* gW_hh   = (const float*)d_in[9];
  const float* gb_ih   = (const float*)d_in[10];
  const float* gb_hh   = (const float*)d_in[11];
  const float* W_neigh = (const float*)d_in[12];
  const float* W_loop  = (const float*)d_in[13];
  const float* W_evolve= (const float*)d_in[14];
  const float* W_hp    = (const float*)d_in[15];
  const float* b_hp    = (const float*)d_in[16];
  const float* W_v     = (const float*)d_in[17];
  const float* b_v     = (const float*)d_in[18];
  const float* W_o     = (const float*)d_in[19];
  const float* b_o     = (const float*)d_in[20];
  const float* time_W  = (const float*)d_in[21];
  const float* time_b  = (const float*)d_in[22];
  const float* glob_W  = (const float*)d_in[23];
  const float* glob_b  = (const float*)d_in[24];
  float* out = (float*)d_out;
  (void)in_sizes; (void)n_in; (void)out_size; (void)ws_size;

  char* ws = (char*)d_ws;
  size_t off = 0;
  auto allocB = [&](size_t bytes)->char*{
    char* pp = ws + off; off += (bytes + 255) & ~(size_t)255;
    return pp;
  };
  float*  tmp    = (float*) allocB(NHf*4);          // Amean (bf16, 1st half) + sgate (bf16, 2nd half)
  bf16_t* h_bf   = (bf16_t*)allocB(NHf*2);          // recurrent state (bf16)
  bf16_t* nh_bf  = (bf16_t*)allocB(NHf*2);          // layer-0 out; aliased: attn_bf
  bf16_t* nh2_bf = (bf16_t*)allocB(NHf*2);
  bf16_t* gh_bf  = (bf16_t*)allocB(NHf*2);
  bf16_t* Amean  = (bf16_t*)tmp;
  bf16_t* sgate  = (bf16_t*)(tmp + NHf/2);
  bf16_t* attn_bf= nh_bf;

  float*  h0    = (float*) allocB((size_t)RR*HH*4);
  bf16_t* h0b   = (bf16_t*)allocB((size_t)RR*HH*2);
  bf16_t* meanb = (bf16_t*)allocB((size_t)RR*HH*2);
  float*  gi0   = (float*) allocB((size_t)RR*768*4);
  float*  gi    = (float*) allocB((size_t)RR*768*4);
  float*  ghb   = (float*) allocB((size_t)RR*768*4);
  bf16_t* wihAT = (bf16_t*)allocB((size_t)768*256*2);
  bf16_t* wihBT = (bf16_t*)allocB((size_t)768*256*2);
  bf16_t* whhT  = (bf16_t*)allocB((size_t)768*256*2);
  float*  WP    = (float*) allocB((size_t)PP*HH*4);
  float*  WovF  = (float*) allocB((size_t)HH*HH*4);
  float*  b_ov  = (float*) allocB((size_t)HH*4);
  bf16_t* bst3  = (bf16_t*)allocB((size_t)2*HH*768*2);   // per-layer [Wn|Wl|Wd]^T, ld 768
  bf16_t* whpT  = (bf16_t*)allocB((size_t)HH*HH*2);
  bf16_t* wovT  = (bf16_t*)allocB((size_t)HH*HH*2);
  bf16_t* timT  = (bf16_t*)allocB((size_t)HH*HH*2);
  bf16_t* globT = (bf16_t*)allocB((size_t)HH*HH*2);
  bf16_t* zrow  = (bf16_t*)allocB(512);                  // one zeroed 256-elem bf16 row
  int* cnt    = (int*)allocB((size_t)(NBIN3+4)*4);
  int* start  = (int*)allocB((size_t)(NBIN3+1)*4);
  int* cur    = (int*)allocB((size_t)NBIN3*4);
  int* rnode  = (int*)allocB((size_t)3*EE*4);
  unsigned* dpack = (unsigned*)allocB((size_t)3*EE*4);
  int* bsum   = (int*)allocB(256*4);
  int* boff   = (int*)allocB(256*4);

  const int MT2 = (NN + 63)/64;              // 782 row tiles (BM=64)
  const int NB3 = (NBIN3 + 1023)/1024;       // 148 scan blocks

  // ---- setup: weight prep + initial h/h0 + gi0 ----
  hipMemsetAsync(zrow, 0, 512, stream);
  copyall_k<<<dim3(768,5), 256, 0, stream>>>(gW_ih, gW_hh, W_hp, emb_rel,
                                             wihAT, wihBT, whhT, whpT, h0b);
  tconv_all_k<<<dim3(8,8,8), 256, 0, stream>>>(W_neigh, W_loop, W_evolve, time_W, glob_W,
                                               bst3, timT, globT);
  misc_k<<<2, 256, 0, stream>>>(W_hp, WP, W_o, b_v, b_o, b_ov);
  sgemm_k<<<dim3(2,4), 256, 0, stream>>>(W_o, W_v, WovF, 256, 256, 256);
  copy_bfw_k<<<HH, 256, 0, stream>>>(WovF, wovT);
  l2norm_k<<<NN, 256, 0, stream>>>(dyn_emb, h_bf);
  hipMemcpyAsync(h0, emb_rel, (size_t)RR*HH*4, hipMemcpyDeviceToDevice, stream);
  // gi0 = emb_rel @ W_ih[:, :256]^T + b_ih   (h0b == emb_rel bf16 at this point)
  mgemm_k<0,1><<<dim3(4,6), 256, 0, stream>>>(h0b, wihAT, gi0, gb_ih, RR, 768, 256, nullptr);

  // ---- batched CSR build for all 3 snapshots ----
  hipMemsetAsync(cnt, 0, (size_t)(NBIN3+4)*4, stream);
  hist3_k<<<(6*EE+255)/256, 256, 0, stream>>>(r_seg, dst, cnt);
  scan1_k<<<NB3, 1024, 0, stream>>>(cnt, start, bsum, NBIN3);
  scan2_k<<<1, 256, 0, stream>>>(bsum, boff, start, NB3, NBIN3);
  scan3_k<<<NB3, 1024, 0, stream>>>(start, cur, boff, NBIN3);
  fill3_k<<<(6*EE+255)/256, 256, 0, stream>>>(r_seg, r_to_e, dst, src, etype, cur, rnode, dpack);

  for (int t=0; t<TT; t++){
    const float* posT = pos_enc + (size_t)t*NN*PP;
    const int* startT = start + (size_t)t*NBIN;
    const int* degT   = cnt + (size_t)t*NBIN + RR;

    // ---- relation mean + GRU ----
    rmean_k<<<RR, 256, 0, stream>>>(startT, rnode, h_bf, meanb, EE*t);
    mgemm_k<8,0><<<dim3(4,6), 256, 0, stream>>>(meanb, wihBT, gi, nullptr, RR, 768, 256, gi0);
    mgemm_k<0,1><<<dim3(4,6), 256, 0, stream>>>(h0b, whhT, ghb, gb_hh, RR, 768, 256, nullptr);
    gru_gate_k<<<RR, 256, 0, stream>>>(gi, ghb, h0, h0b);

    // ---- RGCN layer 0 (single K=768 GEMM, deg0 handled by conditional 3rd A-segment) ----
    gatherM_k<<<(NN+3)/4, 256, 0, stream>>>(h_bf, h0b, startT, dpack, Amean, EE*(t+1));
    mgemm2_k<6,0,1,0,2><<<MT2, 512, 0, stream>>>(Amean, h_bf, bst3, nullptr, nh_bf, nullptr,
        NN, 768, nullptr, nullptr, nullptr, nullptr, degT, zrow);

    // ---- RGCN layer 1 ----
    gatherM_k<<<(NN+3)/4, 256, 0, stream>>>(nh_bf, h0b, startT, dpack, Amean, EE*(t+1));
    mgemm2_k<6,0,1,0,2><<<MT2, 512, 0, stream>>>(Amean, nh_bf, bst3 + (size_t)HH*768, nullptr, nh2_bf, nullptr,
        NN, 768, nullptr, nullptr, nullptr, nullptr, degT, zrow);

    // ---- attention chain ----
    mgemm2_k<2,0,1,1,0><<<MT2, 512, 0, stream>>>(nh2_bf, nullptr, whpT, nullptr, attn_bf, b_hp,
        NN, 256, posT, WP, nullptr, nullptr, nullptr, nullptr);
    mgemm2_k<0,0,1,1,0><<<MT2, 512, 0, stream>>>(attn_bf, nullptr, wovT, nullptr, gh_bf, b_ov,
        NN, 256, nullptr, nullptr, nullptr, nullptr, nullptr, nullptr);

    // ---- time gate (sigmoid in epilogue, bf16), fused norm+update (in-place bf16 h), glob+blend ----
    mgemm2_k<7,0,1,1,0><<<MT2, 512, 0, stream>>>(h_bf, nullptr, timT, nullptr, sgate, time_b,
        NN, 256, nullptr, nullptr, nullptr, nullptr, nullptr, nullptr);
    l2up_k<<<NN, 256, 0, stream>>>(nh2_bf, sgate, h_bf);
    mgemm2_k<3,1,0,1,0><<<MT2, 512, 0, stream>>>(h_bf, nullptr, globT, out + (size_t)t*NHf, nullptr, glob_b,
        NN, 256, nullptr, nullptr, gh_bf, h_bf, nullptr, nullptr);
  }
}